// Round 2
// baseline (611.315 us; speedup 1.0000x reference)
//
#include <hip/hip_runtime.h>
#include <hip/hip_bf16.h>

typedef __hip_bfloat16 bf16;

#define NN 128
#define DD_ 64
#define HH_ 8
#define DH_ 64
#define DI_ 512
#define SS_ 5
#define MLPD 1024
#define SDI 2560

#define BF16_MAGIC 0x3F803F80u

__device__ __forceinline__ float b2f(bf16 x) { return __bfloat162float(x); }

__device__ __forceinline__ float wave_sum64(float v) {
#pragma unroll
    for (int off = 32; off > 0; off >>= 1) v += __shfl_xor(v, off, 64);
    return v;
}

// K0: dtype-adaptive convert src -> fp32. magic = first dword of g_hi (all ones).
__global__ void k_conv(const void* __restrict__ src, float* __restrict__ dst, int n,
                       const unsigned int* __restrict__ magic) {
    bool isbf = (*magic == BF16_MAGIC);
    int i = blockIdx.x * blockDim.x + threadIdx.x;
    int stride = gridDim.x * blockDim.x;
    if (isbf) {
        const bf16* s = (const bf16*)src;
        for (; i < n; i += stride) dst[i] = b2f(s[i]);
    } else {
        const float* s = (const float*)src;
        for (; i < n; i += stride) dst[i] = s[i];
    }
}

// K1: layernorm -> hi, hj (fp32). grid(128), block(64)
__global__ void k_ln(const float* __restrict__ h, const float* __restrict__ ghi,
                     const float* __restrict__ ghj, float* __restrict__ hi, float* __restrict__ hj) {
    int i = blockIdx.x, d = threadIdx.x;
    float x = h[i * DD_ + d];
    float s = wave_sum64(x);
    float s2 = wave_sum64(x * x);
    float m = s * (1.0f / DD_);
    float v = s2 * (1.0f / DD_) - m * m;
    float r = rsqrtf(v + 1e-5f);
    float xc = (x - m) * r;
    hi[i * DD_ + d] = xc * ghi[d];
    hj[i * DD_ + d] = xc * ghj[d];
}

// K2: q = hi@Wq, k = hj@Wk. grid(128), block(512)
__global__ void k_qk(const float* __restrict__ hi, const float* __restrict__ hj,
                     const float* __restrict__ Wq, const float* __restrict__ Wk,
                     float* __restrict__ q, float* __restrict__ k) {
    int i = blockIdx.x, t = threadIdx.x;
    __shared__ float hib[DD_], hjb[DD_];
    if (t < DD_) hib[t] = hi[i * DD_ + t];
    else if (t < 2 * DD_) hjb[t - DD_] = hj[i * DD_ + (t - DD_)];
    __syncthreads();
    float aq = 0.f, ak = 0.f;
#pragma unroll 8
    for (int d = 0; d < DD_; d++) {
        aq += hib[d] * Wq[d * DI_ + t];
        ak += hjb[d] * Wk[d * DI_ + t];
    }
    q[i * DI_ + t] = aq;
    k[i * DI_ + t] = ak;
}

// K3: a1 = silu(hj@Wv1+bv1), p1 = silu(hj@Wp1+bp1). grid(128,2), block(256)
__global__ void k_mlp1(const float* __restrict__ hj, const float* __restrict__ Wv1,
                       const float* __restrict__ bv1, const float* __restrict__ Wp1,
                       const float* __restrict__ bp1, float* __restrict__ a1, float* __restrict__ p1) {
    int j = blockIdx.x, t = threadIdx.x;
    const float* W = blockIdx.y ? Wp1 : Wv1;
    const float* b = blockIdx.y ? bp1 : bv1;
    float* dst = blockIdx.y ? p1 : a1;
    __shared__ float hb[DD_];
    if (t < DD_) hb[t] = hj[j * DD_ + t];
    __syncthreads();
    float acc[4] = {0.f, 0.f, 0.f, 0.f};
    for (int d = 0; d < DD_; d++) {
        float hv = hb[d];
#pragma unroll
        for (int r = 0; r < 4; r++) acc[r] += hv * W[d * MLPD + t + r * 256];
    }
#pragma unroll
    for (int r = 0; r < 4; r++) {
        float x = acc[r] + b[t + r * 256];
        dst[j * MLPD + t + r * 256] = x / (1.0f + expf(-x));
    }
}

// K4: vals = a1@Wv2+bv2, pav = p1@Wp2+bp2. grid(32,2), block(256), 4 j-rows per block
__global__ void k_mlp2(const float* __restrict__ a1, const float* __restrict__ p1,
                       const float* __restrict__ Wv2, const float* __restrict__ bv2,
                       const float* __restrict__ Wp2, const float* __restrict__ bp2,
                       float* __restrict__ vals, float* __restrict__ pav) {
    int j0 = blockIdx.x * 4, t = threadIdx.x;
    const float* src = blockIdx.y ? p1 : a1;
    const float* W = blockIdx.y ? Wp2 : Wv2;
    const float* b = blockIdx.y ? bp2 : bv2;
    float* dst = blockIdx.y ? pav : vals;
    __shared__ float ab[4 * MLPD];
#pragma unroll
    for (int r = 0; r < 16; r++) ab[t + r * 256] = src[j0 * MLPD + t + r * 256];
    __syncthreads();
    float acc[4][10];
#pragma unroll
    for (int jj = 0; jj < 4; jj++)
#pragma unroll
        for (int r = 0; r < 10; r++) acc[jj][r] = 0.f;
    for (int m = 0; m < MLPD; m++) {
        float wv[10];
#pragma unroll
        for (int r = 0; r < 10; r++) wv[r] = W[m * SDI + t + r * 256];
#pragma unroll
        for (int jj = 0; jj < 4; jj++) {
            float av = ab[jj * MLPD + m];
#pragma unroll
            for (int r = 0; r < 10; r++) acc[jj][r] += av * wv[r];
        }
    }
#pragma unroll
    for (int jj = 0; jj < 4; jj++)
#pragma unroll
        for (int r = 0; r < 10; r++)
            dst[(j0 + jj) * SDI + t + r * 256] = acc[jj][r] + b[t + r * 256];
}

// K5: VC[j][s][h][dd] = sum_d vals[j, s*512+h*64+d] * Wc[h*64+d, dd]. grid(128,5), block(512)
__global__ void k_vc(const float* __restrict__ vals, const float* __restrict__ Wc,
                     float* __restrict__ VC) {
    int j = blockIdx.x, s = blockIdx.y, t = threadIdx.x;
    int hh = t >> 6, dd = t & 63;
    __shared__ float vb[DI_];
    vb[t] = vals[j * SDI + s * DI_ + t];
    __syncthreads();
    float acc = 0.f;
#pragma unroll 8
    for (int d = 0; d < DH_; d++) acc += vb[hh * DH_ + d] * Wc[(hh * DH_ + d) * DD_ + dd];
    VC[((j * SS_ + s) * HH_ + hh) * DH_ + dd] = acc;
}

// K6: T[i][c] = sum_j t_ij[i,j,c]. grid(128), block(64)
__global__ void k_tsum(const float* __restrict__ tij, float* __restrict__ T) {
    int i = blockIdx.x, c = threadIdx.x;
    float s = 0.f;
    for (int j = 0; j < NN; j++) s += tij[(i * NN + j) * DD_ + c];
    T[i * DD_ + c] = s;
}

// K7: sn[i][h][j] = sum_d q[i,h*64+d]*k[j,h*64+d]. grid(128,8), block(128)
__global__ void k_simnum(const float* __restrict__ q, const float* __restrict__ k,
                         float* __restrict__ sn) {
    int i = blockIdx.x, hh = blockIdx.y, j = threadIdx.x;
    __shared__ float qb[DH_];
    if (j < DH_) qb[j] = q[i * DI_ + hh * DH_ + j];
    __syncthreads();
    float a = 0.f;
    const float* kr = &k[j * DI_ + hh * DH_];
#pragma unroll 8
    for (int d = 0; d < DH_; d++) a += qb[d] * kr[d];
    sn[i * 1024 + hh * NN + j] = a;
}

// K8a: EV[i][u] = sum_c T[i,c]*Wev[c,u]. grid(128,10), block(256)
__global__ void k_evsum(const float* __restrict__ T, const float* __restrict__ Wev,
                        float* __restrict__ EV) {
    int i = blockIdx.x, t = threadIdx.x;
    int u = blockIdx.y * 256 + t;
    __shared__ float Tb[DD_];
    if (t < DD_) Tb[t] = T[i * DD_ + t];
    __syncthreads();
    float a = 0.f;
#pragma unroll 8
    for (int c = 0; c < DD_; c++) a += Tb[c] * Wev[c * SDI + u];
    EV[i * SDI + u] = a;
}

// K8b: rsd[i][h][s] = 1 / (sum_d q[i,h*64+d]*EV[i,s*512+h*64+d]). grid(128,10), block(256)
__global__ void k_rsd(const float* __restrict__ q, const float* __restrict__ EV,
                      float* __restrict__ rsd) {
    int i = blockIdx.x, t = threadIdx.x;
    int wave = t >> 6, lane = t & 63;
    int p = blockIdx.y * 4 + wave;  // 0..39
    int hh = p / SS_, s = p % SS_;
    float v = q[i * DI_ + hh * DH_ + lane] * EV[i * SDI + s * DI_ + hh * DH_ + lane];
    v = wave_sum64(v);
    if (lane == 0) rsd[i * 40 + hh * SS_ + s] = 1.0f / v;
}

// K9: M[j][s][c][dd] = sum_u Wev[c, s*512+u]*pav[j, s*512+u]*Wc[u, dd]. grid(128,5), block(256)
__global__ void k_M(const float* __restrict__ pav, const float* __restrict__ Wev,
                    const float* __restrict__ Wc, float* __restrict__ M) {
    int j = blockIdx.x, s = blockIdx.y, t = threadIdx.x;
    __shared__ float P[DI_];
    __shared__ __align__(16) float At[64][68];
    __shared__ __align__(16) float Bt[64][68];
    P[t] = pav[j * SDI + s * DI_ + t];
    P[t + 256] = pav[j * SDI + s * DI_ + t + 256];
    int c0 = (t >> 4) * 4, d0 = (t & 15) * 4;
    float acc[4][4];
#pragma unroll
    for (int ci = 0; ci < 4; ci++)
#pragma unroll
        for (int di = 0; di < 4; di++) acc[ci][di] = 0.f;
    for (int u0 = 0; u0 < DI_; u0 += 64) {
        __syncthreads();
#pragma unroll
        for (int r = 0; r < 16; r++) {
            int e = t + r * 256;
            int cA = e >> 6, uA = e & 63;
            At[uA][cA] = Wev[cA * SDI + s * DI_ + u0 + uA] * P[u0 + uA];
            Bt[cA][uA] = Wc[(u0 + cA) * DD_ + uA];  // cA plays 'u', uA plays 'dd'
        }
        __syncthreads();
        for (int u = 0; u < 64; u++) {
            float4 av = *reinterpret_cast<const float4*>(&At[u][c0]);
            float4 bv = *reinterpret_cast<const float4*>(&Bt[u][d0]);
            float a[4] = {av.x, av.y, av.z, av.w};
            float bb[4] = {bv.x, bv.y, bv.z, bv.w};
#pragma unroll
            for (int ci = 0; ci < 4; ci++)
#pragma unroll
                for (int di = 0; di < 4; di++) acc[ci][di] += a[ci] * bb[di];
        }
    }
    float* Mp = &M[(j * SS_ + s) * 4096];
#pragma unroll
    for (int ci = 0; ci < 4; ci++) {
        float4 v = make_float4(acc[ci][0], acc[ci][1], acc[ci][2], acc[ci][3]);
        *reinterpret_cast<float4*>(&Mp[(c0 + ci) * 64 + d0]) = v;
    }
}

// K10: out[i][j][s][dd] = A + E. grid(128,5), block(256) = 4 waves (il = wave, dd = lane)
__global__ void k_out(const float* __restrict__ M, const float* __restrict__ VC,
                      const float* __restrict__ sn, const float* __restrict__ rsd,
                      const float* __restrict__ tij, float* __restrict__ outb) {
    int j = blockIdx.x, s = blockIdx.y, t = threadIdx.x;
    int il = t >> 6, dd = t & 63;
    __shared__ float Ml[4096];
    __shared__ float VCl[DI_];
    __shared__ float tl[4][64];
    __shared__ float snl[4][8];
    __shared__ float rl[4][8];
    const float4* Msrc = reinterpret_cast<const float4*>(&M[(j * SS_ + s) * 4096]);
    float4* Mdst = reinterpret_cast<float4*>(Ml);
#pragma unroll
    for (int r = 0; r < 4; r++) Mdst[t + r * 256] = Msrc[t + r * 256];
    VCl[t] = VC[(j * SS_ + s) * DI_ + t];
    VCl[t + 256] = VC[(j * SS_ + s) * DI_ + t + 256];
    __syncthreads();
    for (int ib = 0; ib < NN; ib += 4) {
        int i = ib + il;
        tl[il][dd] = tij[(i * NN + j) * DD_ + dd];
        if (dd < 8) {
            snl[il][dd] = sn[i * 1024 + dd * NN + j];
            rl[il][dd] = rsd[i * 40 + dd * SS_ + s];
        }
        __syncthreads();
        float A = 0.f;
#pragma unroll
        for (int hh = 0; hh < HH_; hh++) A += snl[il][hh] * rl[il][hh] * VCl[hh * DH_ + dd];
        float E = 0.f;
#pragma unroll
        for (int c = 0; c < 64; c++) E += tl[il][c] * Ml[c * 64 + dd];
        outb[((i * NN + j) * SS_ + s) * 64 + dd] = A + E;
        __syncthreads();
    }
}

// K11: final reductions over j + combine + adaptive-dtype store. grid(128), block(320)
__global__ void k_red(const float* __restrict__ outb, const float* __restrict__ h,
                      const float* __restrict__ r1, const float* __restrict__ r2,
                      const float* __restrict__ x1, const float* __restrict__ x2,
                      void* __restrict__ dstv, const unsigned int* __restrict__ magic) {
    bool isbf = (*magic == BF16_MAGIC);
    int i = blockIdx.x, t = threadIdx.x;
    int s = t >> 6, dd = t & 63;
    __shared__ float r1l[3], r2l[5];
    __shared__ float comb0[64 * 3], comb1[64 * 5];
    float hacc = 0.f;
    float am[5] = {0.f, 0.f, 0.f, 0.f, 0.f};
    for (int j = 0; j < NN; j++) {
        __syncthreads();
        if (t < 3) r1l[t] = r1[(i * NN + j) * 3 + t];
        else if (t < 8) r2l[t - 3] = r2[(i * NN + j) * 5 + (t - 3)];
        __syncthreads();
        float ov = outb[((i * NN + j) * SS_ + s) * 64 + dd];
        if (s == 0) {
            hacc += ov;
        } else if (s == 1) {
#pragma unroll
            for (int m = 0; m < 3; m++) am[m] += r1l[m] * ov;
        } else if (s == 2) {
#pragma unroll
            for (int m = 0; m < 5; m++) am[m] += r2l[m] * ov;
        } else if (s == 3) {
#pragma unroll
            for (int m = 0; m < 3; m++) am[m] += x1[(j * DD_ + dd) * 3 + m] * ov;
        } else {
#pragma unroll
            for (int m = 0; m < 5; m++) am[m] += x2[(j * DD_ + dd) * 5 + m] * ov;
        }
    }
    __syncthreads();
    if (s == 1) {
#pragma unroll
        for (int m = 0; m < 3; m++) comb0[dd * 3 + m] = am[m];
    } else if (s == 2) {
#pragma unroll
        for (int m = 0; m < 5; m++) comb1[dd * 5 + m] = am[m];
    }
    __syncthreads();
    bf16* db = (bf16*)dstv;
    float* df = (float*)dstv;
    if (s == 0) {
        float v = h[i * DD_ + dd] + hacc;
        if (isbf) db[i * DD_ + dd] = __float2bfloat16(v);
        else df[i * DD_ + dd] = v;
    } else if (s == 3) {
#pragma unroll
        for (int m = 0; m < 3; m++) {
            float v = am[m] + comb0[dd * 3 + m];
            int idx = 8192 + (i * DD_ + dd) * 3 + m;
            if (isbf) db[idx] = __float2bfloat16(v);
            else df[idx] = v;
        }
    } else if (s == 4) {
#pragma unroll
        for (int m = 0; m < 5; m++) {
            float v = am[m] + comb1[dd * 5 + m];
            int idx = 8192 + 24576 + (i * DD_ + dd) * 5 + m;
            if (isbf) db[idx] = __float2bfloat16(v);
            else df[idx] = v;
        }
    }
}

extern "C" void kernel_launch(void* const* d_in, const int* in_sizes, int n_in,
                              void* d_out, int out_size, void* d_ws, size_t ws_size,
                              hipStream_t stream) {
    const unsigned int* magic = (const unsigned int*)d_in[6];  // g_hi = ones

    float* w = (float*)d_ws;
    size_t off = 16;  // keep offset 0 free / aligned
    auto alloc = [&](size_t n) { float* p = w + off; off += n; return p; };

    // converted fp32 inputs
    float* hC   = alloc(8192);
    float* tijC = alloc(1048576);
    float* r1C  = alloc(49152);
    float* r2C  = alloc(81920);
    float* x1C  = alloc(24576);
    float* x2C  = alloc(40960);
    float* ghiC = alloc(64);
    float* ghjC = alloc(64);
    float* WqC  = alloc(32768);
    float* WkC  = alloc(32768);
    float* Wv1C = alloc(65536);
    float* bv1C = alloc(1024);
    float* Wv2C = alloc(2621440);
    float* bv2C = alloc(2560);
    float* Wp1C = alloc(65536);
    float* bp1C = alloc(1024);
    float* Wp2C = alloc(2621440);
    float* bp2C = alloc(2560);
    float* WevC = alloc(163840);
    float* WcC  = alloc(32768);
    // pipeline buffers
    float* hi   = alloc(8192);
    float* hj   = alloc(8192);
    float* q    = alloc(65536);
    float* k    = alloc(65536);
    float* a1   = alloc(131072);
    float* p1   = alloc(131072);
    float* vals = alloc(327680);
    float* pav  = alloc(327680);
    float* VC   = alloc(327680);
    float* T    = alloc(8192);
    float* sn   = alloc(131072);
    float* EV   = alloc(327680);
    float* rsd  = alloc(5120);
    float* M    = alloc(2621440);
    float* outb = alloc(5242880);

    float* convDst[20] = {hC, tijC, r1C, r2C, x1C, x2C, ghiC, ghjC, WqC, WkC,
                          Wv1C, bv1C, Wv2C, bv2C, Wp1C, bp1C, Wp2C, bp2C, WevC, WcC};
    for (int idx = 0; idx < 20; idx++) {
        int n = in_sizes[idx];
        int blocks = (n + 255) / 256;
        if (blocks > 1024) blocks = 1024;
        k_conv<<<dim3(blocks), dim3(256), 0, stream>>>(d_in[idx], convDst[idx], n, magic);
    }

    k_ln<<<dim3(128), dim3(64), 0, stream>>>(hC, ghiC, ghjC, hi, hj);
    k_qk<<<dim3(128), dim3(512), 0, stream>>>(hi, hj, WqC, WkC, q, k);
    k_mlp1<<<dim3(128, 2), dim3(256), 0, stream>>>(hj, Wv1C, bv1C, Wp1C, bp1C, a1, p1);
    k_mlp2<<<dim3(32, 2), dim3(256), 0, stream>>>(a1, p1, Wv2C, bv2C, Wp2C, bp2C, vals, pav);
    k_vc<<<dim3(128, 5), dim3(512), 0, stream>>>(vals, WcC, VC);
    k_tsum<<<dim3(128), dim3(64), 0, stream>>>(tijC, T);
    k_simnum<<<dim3(128, 8), dim3(128), 0, stream>>>(q, k, sn);
    k_evsum<<<dim3(128, 10), dim3(256), 0, stream>>>(T, WevC, EV);
    k_rsd<<<dim3(128, 10), dim3(256), 0, stream>>>(q, EV, rsd);
    k_M<<<dim3(128, 5), dim3(256), 0, stream>>>(pav, WevC, WcC, M);
    k_out<<<dim3(128, 5), dim3(256), 0, stream>>>(M, VC, sn, rsd, tijC, outb);
    k_red<<<dim3(128), dim3(320), 0, stream>>>(outb, hC, r1C, r2C, x1C, x2C, d_out, magic);
}

// Round 3
// 384.707 us; speedup vs baseline: 1.5890x; 1.5890x over previous
//
#include <hip/hip_runtime.h>
#include <hip/hip_bf16.h>

typedef __hip_bfloat16 bf16;

#define NN 128
#define DD_ 64
#define HH_ 8
#define DH_ 64
#define DI_ 512
#define SS_ 5
#define MLPD 1024
#define SDI 2560

__device__ __forceinline__ float wave_sum64(float v) {
#pragma unroll
    for (int off = 32; off > 0; off >>= 1) v += __shfl_xor(v, off, 64);
    return v;
}

// K1: layernorm -> hi, hj (fp32). grid(128), block(64)
__global__ void k_ln(const float* __restrict__ h, const float* __restrict__ ghi,
                     const float* __restrict__ ghj, float* __restrict__ hi, float* __restrict__ hj) {
    int i = blockIdx.x, d = threadIdx.x;
    float x = h[i * DD_ + d];
    float s = wave_sum64(x);
    float s2 = wave_sum64(x * x);
    float m = s * (1.0f / DD_);
    float v = s2 * (1.0f / DD_) - m * m;
    float r = rsqrtf(v + 1e-5f);
    float xc = (x - m) * r;
    hi[i * DD_ + d] = xc * ghi[d];
    hj[i * DD_ + d] = xc * ghj[d];
}

// K2: q = hi@Wq, k = hj@Wk. grid(128), block(512)
__global__ void k_qk(const float* __restrict__ hi, const float* __restrict__ hj,
                     const float* __restrict__ Wq, const float* __restrict__ Wk,
                     float* __restrict__ q, float* __restrict__ k) {
    int i = blockIdx.x, t = threadIdx.x;
    __shared__ float hib[DD_], hjb[DD_];
    if (t < DD_) hib[t] = hi[i * DD_ + t];
    else if (t < 2 * DD_) hjb[t - DD_] = hj[i * DD_ + (t - DD_)];
    __syncthreads();
    float aq = 0.f, ak = 0.f;
#pragma unroll 8
    for (int d = 0; d < DD_; d++) {
        aq += hib[d] * Wq[d * DI_ + t];
        ak += hjb[d] * Wk[d * DI_ + t];
    }
    q[i * DI_ + t] = aq;
    k[i * DI_ + t] = ak;
}

// K3: a1 = silu(hj@Wv1+bv1), p1 = silu(hj@Wp1+bp1). grid(128,2), block(256)
__global__ void k_mlp1(const float* __restrict__ hj, const float* __restrict__ Wv1,
                       const float* __restrict__ bv1, const float* __restrict__ Wp1,
                       const float* __restrict__ bp1, float* __restrict__ a1, float* __restrict__ p1) {
    int j = blockIdx.x, t = threadIdx.x;
    const float* W = blockIdx.y ? Wp1 : Wv1;
    const float* b = blockIdx.y ? bp1 : bv1;
    float* dst = blockIdx.y ? p1 : a1;
    __shared__ float hb[DD_];
    if (t < DD_) hb[t] = hj[j * DD_ + t];
    __syncthreads();
    float acc[4] = {0.f, 0.f, 0.f, 0.f};
    for (int d = 0; d < DD_; d++) {
        float hv = hb[d];
#pragma unroll
        for (int r = 0; r < 4; r++) acc[r] += hv * W[d * MLPD + t + r * 256];
    }
#pragma unroll
    for (int r = 0; r < 4; r++) {
        float x = acc[r] + b[t + r * 256];
        dst[j * MLPD + t + r * 256] = x / (1.0f + expf(-x));
    }
}

// K4: vals = a1@Wv2+bv2, pav = p1@Wp2+bp2.
// grid(16, 20): x = j-tile (8 rows), y<10 -> v-GEMM col-tile, y>=10 -> p-GEMM. block(256).
#define CH 128
__global__ void k_mlp2(const float* __restrict__ a1, const float* __restrict__ p1,
                       const float* __restrict__ Wv2, const float* __restrict__ bv2,
                       const float* __restrict__ Wp2, const float* __restrict__ bp2,
                       float* __restrict__ vals, float* __restrict__ pav) {
    int jt = blockIdx.x, ct = blockIdx.y, t = threadIdx.x;
    bool isp = ct >= 10;
    int c0 = (isp ? ct - 10 : ct) * 256;
    const float* __restrict__ src = isp ? p1 : a1;
    const float* __restrict__ W = isp ? Wp2 : Wv2;
    const float* __restrict__ b = isp ? bp2 : bv2;
    float* __restrict__ dst = isp ? pav : vals;
    int j0 = jt * 8;
    __shared__ __align__(16) float als[CH][12];
    float acc[8] = {0.f, 0.f, 0.f, 0.f, 0.f, 0.f, 0.f, 0.f};
    float bias = b[c0 + t];
    const float* wp = W + c0 + t;
    for (int m0 = 0; m0 < MLPD; m0 += CH) {
        __syncthreads();
        {
            int m = t & 127;
            int jj0 = (t >> 7) * 4;
#pragma unroll
            for (int r = 0; r < 4; r++)
                als[m][jj0 + r] = src[(j0 + jj0 + r) * MLPD + m0 + m];
        }
        __syncthreads();
#pragma unroll 4
        for (int m = 0; m < CH; m++) {
            float w = wp[(size_t)(m0 + m) * SDI];
            float4 a0 = *reinterpret_cast<const float4*>(&als[m][0]);
            float4 a4 = *reinterpret_cast<const float4*>(&als[m][4]);
            acc[0] += a0.x * w; acc[1] += a0.y * w; acc[2] += a0.z * w; acc[3] += a0.w * w;
            acc[4] += a4.x * w; acc[5] += a4.y * w; acc[6] += a4.z * w; acc[7] += a4.w * w;
        }
    }
#pragma unroll
    for (int jj = 0; jj < 8; jj++)
        dst[(j0 + jj) * SDI + c0 + t] = acc[jj] + bias;
}

// K5: VC[j][s][h][dd] = sum_d vals[j, s*512+h*64+d] * Wc[h*64+d, dd]. grid(128,5), block(512)
__global__ void k_vc(const float* __restrict__ vals, const float* __restrict__ Wc,
                     float* __restrict__ VC) {
    int j = blockIdx.x, s = blockIdx.y, t = threadIdx.x;
    int hh = t >> 6, dd = t & 63;
    __shared__ float vb[DI_];
    vb[t] = vals[j * SDI + s * DI_ + t];
    __syncthreads();
    float acc = 0.f;
#pragma unroll 8
    for (int d = 0; d < DH_; d++) acc += vb[hh * DH_ + d] * Wc[(hh * DH_ + d) * DD_ + dd];
    VC[((j * SS_ + s) * HH_ + hh) * DH_ + dd] = acc;
}

// K6: T[i][c] = sum_j t_ij[i,j,c]. grid(128), block(64)
__global__ void k_tsum(const float* __restrict__ tij, float* __restrict__ T) {
    int i = blockIdx.x, c = threadIdx.x;
    float s = 0.f;
    for (int j = 0; j < NN; j++) s += tij[(i * NN + j) * DD_ + c];
    T[i * DD_ + c] = s;
}

// K7: sn[i][h][j] = sum_d q[i,h*64+d]*k[j,h*64+d]. grid(128,8), block(128)
__global__ void k_simnum(const float* __restrict__ q, const float* __restrict__ k,
                         float* __restrict__ sn) {
    int i = blockIdx.x, hh = blockIdx.y, j = threadIdx.x;
    __shared__ float qb[DH_];
    if (j < DH_) qb[j] = q[i * DI_ + hh * DH_ + j];
    __syncthreads();
    float a = 0.f;
    const float* kr = &k[j * DI_ + hh * DH_];
#pragma unroll 8
    for (int d = 0; d < DH_; d++) a += qb[d] * kr[d];
    sn[i * 1024 + hh * NN + j] = a;
}

// K8a: EV[i][u] = sum_c T[i,c]*Wev[c,u]. grid(128,10), block(256)
__global__ void k_evsum(const float* __restrict__ T, const float* __restrict__ Wev,
                        float* __restrict__ EV) {
    int i = blockIdx.x, t = threadIdx.x;
    int u = blockIdx.y * 256 + t;
    __shared__ float Tb[DD_];
    if (t < DD_) Tb[t] = T[i * DD_ + t];
    __syncthreads();
    float a = 0.f;
#pragma unroll 8
    for (int c = 0; c < DD_; c++) a += Tb[c] * Wev[c * SDI + u];
    EV[i * SDI + u] = a;
}

// K8b: rsd[i][h][s] = 1 / (sum_d q[i,h*64+d]*EV[i,s*512+h*64+d]). grid(128,10), block(256)
__global__ void k_rsd(const float* __restrict__ q, const float* __restrict__ EV,
                      float* __restrict__ rsd) {
    int i = blockIdx.x, t = threadIdx.x;
    int wave = t >> 6, lane = t & 63;
    int p = blockIdx.y * 4 + wave;  // 0..39
    int hh = p / SS_, s = p % SS_;
    float v = q[i * DI_ + hh * DH_ + lane] * EV[i * SDI + s * DI_ + hh * DH_ + lane];
    v = wave_sum64(v);
    if (lane == 0) rsd[i * 40 + hh * SS_ + s] = 1.0f / v;
}

// K9: M[j][s][c][dd] = sum_u Wev[c, s*512+u]*pav[j, s*512+u]*Wc[u, dd]. grid(128,5), block(256)
__global__ void k_M(const float* __restrict__ pav, const float* __restrict__ Wev,
                    const float* __restrict__ Wc, float* __restrict__ M) {
    int j = blockIdx.x, s = blockIdx.y, t = threadIdx.x;
    __shared__ float P[DI_];
    __shared__ __align__(16) float At[64][68];
    __shared__ __align__(16) float Bt[64][68];
    P[t] = pav[j * SDI + s * DI_ + t];
    P[t + 256] = pav[j * SDI + s * DI_ + t + 256];
    int c0 = (t >> 4) * 4, d0 = (t & 15) * 4;
    float acc[4][4];
#pragma unroll
    for (int ci = 0; ci < 4; ci++)
#pragma unroll
        for (int di = 0; di < 4; di++) acc[ci][di] = 0.f;
    for (int u0 = 0; u0 < DI_; u0 += 64) {
        __syncthreads();
#pragma unroll
        for (int r = 0; r < 16; r++) {
            int e = t + r * 256;
            int cA = e >> 6, uA = e & 63;
            At[uA][cA] = Wev[cA * SDI + s * DI_ + u0 + uA] * P[u0 + uA];
            Bt[cA][uA] = Wc[(u0 + cA) * DD_ + uA];  // cA plays 'u', uA plays 'dd'
        }
        __syncthreads();
        for (int u = 0; u < 64; u++) {
            float4 av = *reinterpret_cast<const float4*>(&At[u][c0]);
            float4 bv = *reinterpret_cast<const float4*>(&Bt[u][d0]);
            float a[4] = {av.x, av.y, av.z, av.w};
            float bb[4] = {bv.x, bv.y, bv.z, bv.w};
#pragma unroll
            for (int ci = 0; ci < 4; ci++)
#pragma unroll
                for (int di = 0; di < 4; di++) acc[ci][di] += a[ci] * bb[di];
        }
    }
    float* Mp = &M[(j * SS_ + s) * 4096];
#pragma unroll
    for (int ci = 0; ci < 4; ci++) {
        float4 v = make_float4(acc[ci][0], acc[ci][1], acc[ci][2], acc[ci][3]);
        *reinterpret_cast<float4*>(&Mp[(c0 + ci) * 64 + d0]) = v;
    }
}

// K10: out[i][j][s][dd] = A + E. grid(128,5), block(256) = 4 waves (il = wave, dd = lane).
// All in-loop LDS arrays are indexed by wave id -> wave-internal ordering, no barriers needed.
__global__ void k_out(const float* __restrict__ M, const float* __restrict__ VC,
                      const float* __restrict__ sn, const float* __restrict__ rsd,
                      const float* __restrict__ tij, float* __restrict__ outb) {
    int j = blockIdx.x, s = blockIdx.y, t = threadIdx.x;
    int il = t >> 6, dd = t & 63;
    __shared__ float Ml[4096];
    __shared__ float VCl[DI_];
    __shared__ float tl[4][64];
    __shared__ float snl[4][8];
    __shared__ float rl[4][8];
    const float4* Msrc = reinterpret_cast<const float4*>(&M[(j * SS_ + s) * 4096]);
    float4* Mdst = reinterpret_cast<float4*>(Ml);
#pragma unroll
    for (int r = 0; r < 4; r++) Mdst[t + r * 256] = Msrc[t + r * 256];
    VCl[t] = VC[(j * SS_ + s) * DI_ + t];
    VCl[t + 256] = VC[(j * SS_ + s) * DI_ + t + 256];
    __syncthreads();
    for (int ib = 0; ib < NN; ib += 4) {
        int i = ib + il;
        tl[il][dd] = tij[(i * NN + j) * DD_ + dd];
        if (dd < 8) {
            snl[il][dd] = sn[i * 1024 + dd * NN + j];
            rl[il][dd] = rsd[i * 40 + dd * SS_ + s];
        }
        float A = 0.f;
#pragma unroll
        for (int hh = 0; hh < HH_; hh++) A += snl[il][hh] * rl[il][hh] * VCl[hh * DH_ + dd];
        float E = 0.f;
#pragma unroll
        for (int c = 0; c < 64; c++) E += tl[il][c] * Ml[c * 64 + dd];
        outb[((i * NN + j) * SS_ + s) * 64 + dd] = A + E;
    }
}

// K11: final reductions over j + combine + fp32 store. grid(128), block(320).
// r1/r2 read directly (same-address broadcast loads) -> no per-j barriers.
__global__ void k_red(const float* __restrict__ outb, const float* __restrict__ h,
                      const float* __restrict__ r1, const float* __restrict__ r2,
                      const float* __restrict__ x1, const float* __restrict__ x2,
                      float* __restrict__ dst) {
    int i = blockIdx.x, t = threadIdx.x;
    int s = t >> 6, dd = t & 63;
    __shared__ float comb0[64 * 3], comb1[64 * 5];
    float hacc = 0.f;
    float am[5] = {0.f, 0.f, 0.f, 0.f, 0.f};
    for (int j = 0; j < NN; j++) {
        float ov = outb[((i * NN + j) * SS_ + s) * 64 + dd];
        if (s == 0) {
            hacc += ov;
        } else if (s == 1) {
#pragma unroll
            for (int m = 0; m < 3; m++) am[m] += r1[(i * NN + j) * 3 + m] * ov;
        } else if (s == 2) {
#pragma unroll
            for (int m = 0; m < 5; m++) am[m] += r2[(i * NN + j) * 5 + m] * ov;
        } else if (s == 3) {
#pragma unroll
            for (int m = 0; m < 3; m++) am[m] += x1[(j * DD_ + dd) * 3 + m] * ov;
        } else {
#pragma unroll
            for (int m = 0; m < 5; m++) am[m] += x2[(j * DD_ + dd) * 5 + m] * ov;
        }
    }
    __syncthreads();
    if (s == 1) {
#pragma unroll
        for (int m = 0; m < 3; m++) comb0[dd * 3 + m] = am[m];
    } else if (s == 2) {
#pragma unroll
        for (int m = 0; m < 5; m++) comb1[dd * 5 + m] = am[m];
    }
    __syncthreads();
    if (s == 0) {
        dst[i * DD_ + dd] = h[i * DD_ + dd] + hacc;
    } else if (s == 3) {
#pragma unroll
        for (int m = 0; m < 3; m++)
            dst[8192 + (i * DD_ + dd) * 3 + m] = am[m] + comb0[dd * 3 + m];
    } else if (s == 4) {
#pragma unroll
        for (int m = 0; m < 5; m++)
            dst[8192 + 24576 + (i * DD_ + dd) * 5 + m] = am[m] + comb1[dd * 5 + m];
    }
}

extern "C" void kernel_launch(void* const* d_in, const int* in_sizes, int n_in,
                              void* d_out, int out_size, void* d_ws, size_t ws_size,
                              hipStream_t stream) {
    const float* h_in = (const float*)d_in[0];
    const float* tij = (const float*)d_in[1];
    const float* r1 = (const float*)d_in[2];
    const float* r2 = (const float*)d_in[3];
    const float* x1 = (const float*)d_in[4];
    const float* x2 = (const float*)d_in[5];
    const float* ghi = (const float*)d_in[6];
    const float* ghj = (const float*)d_in[7];
    const float* Wq = (const float*)d_in[8];
    const float* Wk = (const float*)d_in[9];
    const float* Wv1 = (const float*)d_in[10];
    const float* bv1 = (const float*)d_in[11];
    const float* Wv2 = (const float*)d_in[12];
    const float* bv2 = (const float*)d_in[13];
    const float* Wp1 = (const float*)d_in[14];
    const float* bp1 = (const float*)d_in[15];
    const float* Wp2 = (const float*)d_in[16];
    const float* bp2 = (const float*)d_in[17];
    const float* Wev = (const float*)d_in[18];
    const float* Wc = (const float*)d_in[19];
    float* dst = (float*)d_out;

    float* w = (float*)d_ws;
    size_t off = 16;
    auto alloc = [&](size_t n) { float* p = w + off; off += n; return p; };
    float* hi   = alloc(8192);
    float* hj   = alloc(8192);
    float* q    = alloc(65536);
    float* k    = alloc(65536);
    float* a1   = alloc(131072);
    float* p1   = alloc(131072);
    float* vals = alloc(327680);
    float* pav  = alloc(327680);
    float* VC   = alloc(327680);
    float* T    = alloc(8192);
    float* sn   = alloc(131072);
    float* EV   = alloc(327680);
    float* rsd  = alloc(5120);
    float* M    = alloc(2621440);
    float* outb = alloc(5242880);

    k_ln<<<dim3(128), dim3(64), 0, stream>>>(h_in, ghi, ghj, hi, hj);
    k_qk<<<dim3(128), dim3(512), 0, stream>>>(hi, hj, Wq, Wk, q, k);
    k_mlp1<<<dim3(128, 2), dim3(256), 0, stream>>>(hj, Wv1, bv1, Wp1, bp1, a1, p1);
    k_mlp2<<<dim3(16, 20), dim3(256), 0, stream>>>(a1, p1, Wv2, bv2, Wp2, bp2, vals, pav);
    k_vc<<<dim3(128, 5), dim3(512), 0, stream>>>(vals, Wc, VC);
    k_tsum<<<dim3(128), dim3(64), 0, stream>>>(tij, T);
    k_simnum<<<dim3(128, 8), dim3(128), 0, stream>>>(q, k, sn);
    k_evsum<<<dim3(128, 10), dim3(256), 0, stream>>>(T, Wev, EV);
    k_rsd<<<dim3(128, 10), dim3(256), 0, stream>>>(q, EV, rsd);
    k_M<<<dim3(128, 5), dim3(256), 0, stream>>>(pav, Wev, Wc, M);
    k_out<<<dim3(128, 5), dim3(256), 0, stream>>>(M, VC, sn, rsd, tij, outb);
    k_red<<<dim3(128), dim3(320), 0, stream>>>(outb, h_in, r1, r2, x1, x2, dst);
}

// Round 4
// 322.236 us; speedup vs baseline: 1.8971x; 1.1939x over previous
//
#include <hip/hip_runtime.h>
#include <hip/hip_bf16.h>

typedef __hip_bfloat16 bf16;
typedef __attribute__((ext_vector_type(8))) short short8;
typedef __attribute__((ext_vector_type(4))) float f32x4;

#define NN 128
#define DD_ 64
#define HH_ 8
#define DH_ 64
#define DI_ 512
#define SS_ 5
#define MLPD 1024
#define SDI 2560

__device__ __forceinline__ float wave_sum64(float v) {
#pragma unroll
    for (int off = 32; off > 0; off >>= 1) v += __shfl_xor(v, off, 64);
    return v;
}

__device__ __forceinline__ unsigned short f2bf_u(float f) {
    unsigned u = __float_as_uint(f);
    u += 0x7FFF + ((u >> 16) & 1);
    return (unsigned short)(u >> 16);
}
__device__ __forceinline__ float bfu2f(unsigned short s) {
    return __uint_as_float(((unsigned)s) << 16);
}
__device__ __forceinline__ unsigned pk2(unsigned short a, unsigned short b) {
    return (unsigned)a | ((unsigned)b << 16);
}

// K1: layernorm -> hi, hj. grid(128), block(64)
__global__ void k_ln(const float* __restrict__ h, const float* __restrict__ ghi,
                     const float* __restrict__ ghj, float* __restrict__ hi, float* __restrict__ hj) {
    int i = blockIdx.x, d = threadIdx.x;
    float x = h[i * DD_ + d];
    float s = wave_sum64(x);
    float s2 = wave_sum64(x * x);
    float m = s * (1.0f / DD_);
    float v = s2 * (1.0f / DD_) - m * m;
    float r = rsqrtf(v + 1e-5f);
    float xc = (x - m) * r;
    hi[i * DD_ + d] = xc * ghi[d];
    hj[i * DD_ + d] = xc * ghj[d];
}

// K2: q = hi@Wq, k = hj@Wk. grid(128), block(512)
__global__ void k_qk(const float* __restrict__ hi, const float* __restrict__ hj,
                     const float* __restrict__ Wq, const float* __restrict__ Wk,
                     float* __restrict__ q, float* __restrict__ k) {
    int i = blockIdx.x, t = threadIdx.x;
    __shared__ float hib[DD_], hjb[DD_];
    if (t < DD_) hib[t] = hi[i * DD_ + t];
    else if (t < 2 * DD_) hjb[t - DD_] = hj[i * DD_ + (t - DD_)];
    __syncthreads();
    float aq = 0.f, ak = 0.f;
#pragma unroll 8
    for (int d = 0; d < DD_; d++) {
        aq += hib[d] * Wq[d * DI_ + t];
        ak += hjb[d] * Wk[d * DI_ + t];
    }
    q[i * DI_ + t] = aq;
    k[i * DI_ + t] = ak;
}

// K3: a1 = silu(hj@Wv1+bv1), p1 = silu(hj@Wp1+bp1). grid(128,2), block(256)
__global__ void k_mlp1(const float* __restrict__ hj, const float* __restrict__ Wv1,
                       const float* __restrict__ bv1, const float* __restrict__ Wp1,
                       const float* __restrict__ bp1, float* __restrict__ a1, float* __restrict__ p1) {
    int j = blockIdx.x, t = threadIdx.x;
    const float* W = blockIdx.y ? Wp1 : Wv1;
    const float* b = blockIdx.y ? bp1 : bv1;
    float* dst = blockIdx.y ? p1 : a1;
    __shared__ float hb[DD_];
    if (t < DD_) hb[t] = hj[j * DD_ + t];
    __syncthreads();
    float acc[4] = {0.f, 0.f, 0.f, 0.f};
    for (int d = 0; d < DD_; d++) {
        float hv = hb[d];
#pragma unroll
        for (int r = 0; r < 4; r++) acc[r] += hv * W[d * MLPD + t + r * 256];
    }
#pragma unroll
    for (int r = 0; r < 4; r++) {
        float x = acc[r] + b[t + r * 256];
        dst[j * MLPD + t + r * 256] = x / (1.0f + expf(-x));
    }
}

// K4: split-K GEMM: part[ks][j][cc] = sum over k-slice of A[j,k]*W[k,cc]
// combined cc in [0,5120): cc<2560 -> (a1,Wv2), else (p1,Wp2).
// grid(40, 8), block(256). Thread tile 4j x 16c (cols = tc*4 + cf*32 + e).
#define KSP 8
#define KSL 128
__global__ __launch_bounds__(256) void k_mlp2(const float* __restrict__ a1,
                                              const float* __restrict__ p1,
                                              const float* __restrict__ Wv2,
                                              const float* __restrict__ Wp2,
                                              float* __restrict__ part) {
    int ct = blockIdx.x, ks = blockIdx.y, t = threadIdx.x;
    int c0 = ct * 128;
    bool isp = c0 >= 2560;
    int c0l = c0 - (isp ? 2560 : 0);
    const float* __restrict__ src = isp ? p1 : a1;
    const float* __restrict__ W = isp ? Wp2 : Wv2;
    int k0base = ks * KSL;
    __shared__ float As[128][33];
    __shared__ float Ws[32][128];
    int tc = t & 7;
    int tj = t >> 3;
    int j0 = tj * 4;
    float acc[4][16];
#pragma unroll
    for (int jj = 0; jj < 4; jj++)
#pragma unroll
        for (int cc = 0; cc < 16; cc++) acc[jj][cc] = 0.f;
    for (int kc = 0; kc < KSL; kc += 32) {
        int k0 = k0base + kc;
        __syncthreads();
        // stage A: 128 j x 32 k (scalar LDS writes, pad-33 rows -> conflict-free reads)
#pragma unroll
        for (int it = 0; it < 4; it++) {
            int slot = t + it * 256;
            int jj = slot >> 3, f4 = (slot & 7) * 4;
            float4 v = *(const float4*)&src[jj * MLPD + k0 + f4];
            As[jj][f4 + 0] = v.x; As[jj][f4 + 1] = v.y;
            As[jj][f4 + 2] = v.z; As[jj][f4 + 3] = v.w;
        }
        // stage W: 32 k x 128 c
#pragma unroll
        for (int it = 0; it < 4; it++) {
            int slot = t + it * 256;
            int kk = slot >> 5, f4 = (slot & 31) * 4;
            float4 v = *(const float4*)&W[(size_t)(k0 + kk) * SDI + c0l + f4];
            *(float4*)&Ws[kk][f4] = v;
        }
        __syncthreads();
#pragma unroll 4
        for (int k = 0; k < 32; k++) {
            float a[4];
#pragma unroll
            for (int jj = 0; jj < 4; jj++) a[jj] = As[j0 + jj][k];
#pragma unroll
            for (int cf = 0; cf < 4; cf++) {
                float4 wv = *(const float4*)&Ws[k][tc * 4 + cf * 32];
#pragma unroll
                for (int jj = 0; jj < 4; jj++) {
                    acc[jj][cf * 4 + 0] += a[jj] * wv.x;
                    acc[jj][cf * 4 + 1] += a[jj] * wv.y;
                    acc[jj][cf * 4 + 2] += a[jj] * wv.z;
                    acc[jj][cf * 4 + 3] += a[jj] * wv.w;
                }
            }
        }
    }
#pragma unroll
    for (int jj = 0; jj < 4; jj++)
#pragma unroll
        for (int cf = 0; cf < 4; cf++) {
            float4 v = make_float4(acc[jj][cf * 4 + 0], acc[jj][cf * 4 + 1],
                                   acc[jj][cf * 4 + 2], acc[jj][cf * 4 + 3]);
            *(float4*)&part[(size_t)ks * 655360 + (size_t)(j0 + jj) * 5120 + c0 + tc * 4 + cf * 32] = v;
        }
}

// K4b: reduce 8 partials + bias -> vals / pav. grid(640), block(256)
__global__ void k_mred(const float* __restrict__ part, const float* __restrict__ bv2,
                       const float* __restrict__ bp2, float* __restrict__ vals,
                       float* __restrict__ pav) {
    int idx = blockIdx.x * 256 + threadIdx.x;
    int e0 = idx * 4;
    int j = e0 / 5120, cc = e0 % 5120;
    bool isp = cc >= 2560;
    int ccl = cc - (isp ? 2560 : 0);
    float sx = 0.f, sy = 0.f, sz = 0.f, sw = 0.f;
#pragma unroll
    for (int p = 0; p < KSP; p++) {
        float4 v = *(const float4*)&part[(size_t)p * 655360 + e0];
        sx += v.x; sy += v.y; sz += v.z; sw += v.w;
    }
    const float* b = isp ? bp2 : bv2;
    float4 bb = *(const float4*)&b[ccl];
    float* dst = isp ? pav : vals;
    *(float4*)&dst[(size_t)j * SDI + ccl] = make_float4(sx + bb.x, sy + bb.y, sz + bb.z, sw + bb.w);
}

// K5: VC[j][s][h][dd] = sum_d vals[j, s*512+h*64+d] * Wc[h*64+d, dd]. grid(128,5), block(512)
__global__ void k_vc(const float* __restrict__ vals, const float* __restrict__ Wc,
                     float* __restrict__ VC) {
    int j = blockIdx.x, s = blockIdx.y, t = threadIdx.x;
    int hh = t >> 6, dd = t & 63;
    __shared__ float vb[DI_];
    vb[t] = vals[j * SDI + s * DI_ + t];
    __syncthreads();
    float acc = 0.f;
#pragma unroll 8
    for (int d = 0; d < DH_; d++) acc += vb[hh * DH_ + d] * Wc[(hh * DH_ + d) * DD_ + dd];
    VC[((j * SS_ + s) * HH_ + hh) * DH_ + dd] = acc;
}

// K6: T[i][c] = sum_j t_ij[i,j,c]. grid(128), block(256)
__global__ void k_tsum(const float* __restrict__ tij, float* __restrict__ T) {
    int i = blockIdx.x, t = threadIdx.x;
    int c = t & 63, jw = t >> 6;
    float s = 0.f;
    for (int j = jw; j < NN; j += 4) s += tij[(i * NN + j) * DD_ + c];
    __shared__ float red[4][64];
    red[jw][c] = s;
    __syncthreads();
    if (t < 64) T[i * DD_ + t] = red[0][t] + red[1][t] + red[2][t] + red[3][t];
}

// K7: sn[i][h][j] = sum_d q[i,h*64+d]*k[j,h*64+d]. grid(128,8), block(128)
__global__ void k_simnum(const float* __restrict__ q, const float* __restrict__ k,
                         float* __restrict__ sn) {
    int i = blockIdx.x, hh = blockIdx.y, j = threadIdx.x;
    __shared__ float qb[DH_];
    if (j < DH_) qb[j] = q[i * DI_ + hh * DH_ + j];
    __syncthreads();
    float a = 0.f;
    const float* kr = &k[j * DI_ + hh * DH_];
#pragma unroll 8
    for (int d = 0; d < DH_; d++) a += qb[d] * kr[d];
    sn[i * 1024 + hh * NN + j] = a;
}

// K8a: EV[i][u] = sum_c T[i,c]*Wev[c,u]. grid(128,10), block(256)
__global__ void k_evsum(const float* __restrict__ T, const float* __restrict__ Wev,
                        float* __restrict__ EV) {
    int i = blockIdx.x, t = threadIdx.x;
    int u = blockIdx.y * 256 + t;
    __shared__ float Tb[DD_];
    if (t < DD_) Tb[t] = T[i * DD_ + t];
    __syncthreads();
    float a = 0.f;
#pragma unroll 8
    for (int c = 0; c < DD_; c++) a += Tb[c] * Wev[c * SDI + u];
    EV[i * SDI + u] = a;
}

// K8b: rsd[i][h][s] = 1 / sim_den. grid(128,10), block(256)
__global__ void k_rsd(const float* __restrict__ q, const float* __restrict__ EV,
                      float* __restrict__ rsd) {
    int i = blockIdx.x, t = threadIdx.x;
    int wave = t >> 6, lane = t & 63;
    int p = blockIdx.y * 4 + wave;
    int hh = p / SS_, s = p % SS_;
    float v = q[i * DI_ + hh * DH_ + lane] * EV[i * SDI + s * DI_ + hh * DH_ + lane];
    v = wave_sum64(v);
    if (lane == 0) rsd[i * 40 + hh * SS_ + s] = 1.0f / v;
}

// K9: M[j][s][c][dd] = sum_u (Wev[c,s*512+u]*pav[j,s*512+u]) * Wc[u,dd]
// MFMA 16x16x32 bf16 with hi/lo compensation (fp32-accurate).
// grid(128,5), block(256) = 4 waves; wave w owns m-strip c in [w*16, w*16+16).
#define KCM 64
__global__ __launch_bounds__(256) void k_M(const float* __restrict__ pav,
                                           const float* __restrict__ Wev,
                                           const float* __restrict__ Wc,
                                           float* __restrict__ M) {
    int j = blockIdx.x, s = blockIdx.y, t = threadIdx.x;
    int lane = t & 63, w = t >> 6;
    __shared__ float P[DI_];
    __shared__ unsigned short Ahi[64][72], Alo[64][72];
    __shared__ unsigned short Bhi[64][72], Blo[64][72];
    P[t] = pav[j * SDI + s * DI_ + t];
    P[t + 256] = pav[j * SDI + s * DI_ + t + 256];
    f32x4 acc[4];
#pragma unroll
    for (int n = 0; n < 4; n++) acc[n] = (f32x4){0.f, 0.f, 0.f, 0.f};
    __syncthreads();
    for (int u0 = 0; u0 < DI_; u0 += KCM) {
        // ---- stage A' = Wev * p (hi/lo bf16): thread -> (c = t>>2, 16 u)
        {
            int c = t >> 2, ug = (t & 3) * 16;
            const float* wevp = &Wev[(size_t)c * SDI + s * DI_ + u0 + ug];
            unsigned short ah[16], al[16];
#pragma unroll
            for (int e = 0; e < 16; e += 4) {
                float4 wv = *(const float4*)(wevp + e);
                float4 pv = *(const float4*)&P[u0 + ug + e];
                float av[4] = {wv.x * pv.x, wv.y * pv.y, wv.z * pv.z, wv.w * pv.w};
#pragma unroll
                for (int z = 0; z < 4; z++) {
                    unsigned short hh2 = f2bf_u(av[z]);
                    ah[e + z] = hh2;
                    al[e + z] = f2bf_u(av[z] - bfu2f(hh2));
                }
            }
            *(uint4*)&Ahi[c][ug] = make_uint4(pk2(ah[0], ah[1]), pk2(ah[2], ah[3]),
                                              pk2(ah[4], ah[5]), pk2(ah[6], ah[7]));
            *(uint4*)&Ahi[c][ug + 8] = make_uint4(pk2(ah[8], ah[9]), pk2(ah[10], ah[11]),
                                                  pk2(ah[12], ah[13]), pk2(ah[14], ah[15]));
            *(uint4*)&Alo[c][ug] = make_uint4(pk2(al[0], al[1]), pk2(al[2], al[3]),
                                              pk2(al[4], al[5]), pk2(al[6], al[7]));
            *(uint4*)&Alo[c][ug + 8] = make_uint4(pk2(al[8], al[9]), pk2(al[10], al[11]),
                                                  pk2(al[12], al[13]), pk2(al[14], al[15]));
        }
        // ---- stage B = Wc transposed (hi/lo bf16): thread -> (dd = t&63, 16 u)
        {
            int dd = t & 63, ub = (t >> 6) * 16;
            unsigned short bh[16], bl[16];
#pragma unroll
            for (int e = 0; e < 16; e++) {
                float v = Wc[(size_t)(u0 + ub + e) * DD_ + dd];
                unsigned short hh2 = f2bf_u(v);
                bh[e] = hh2;
                bl[e] = f2bf_u(v - bfu2f(hh2));
            }
            *(uint4*)&Bhi[dd][ub] = make_uint4(pk2(bh[0], bh[1]), pk2(bh[2], bh[3]),
                                               pk2(bh[4], bh[5]), pk2(bh[6], bh[7]));
            *(uint4*)&Bhi[dd][ub + 8] = make_uint4(pk2(bh[8], bh[9]), pk2(bh[10], bh[11]),
                                                   pk2(bh[12], bh[13]), pk2(bh[14], bh[15]));
            *(uint4*)&Blo[dd][ub] = make_uint4(pk2(bl[0], bl[1]), pk2(bl[2], bl[3]),
                                               pk2(bl[4], bl[5]), pk2(bl[6], bl[7]));
            *(uint4*)&Blo[dd][ub + 8] = make_uint4(pk2(bl[8], bl[9]), pk2(bl[10], bl[11]),
                                                   pk2(bl[12], bl[13]), pk2(bl[14], bl[15]));
        }
        __syncthreads();
#pragma unroll
        for (int kk = 0; kk < 2; kk++) {
            int ko = kk * 32 + (lane >> 4) * 8;
            short8 a_h = *(const short8*)&Ahi[w * 16 + (lane & 15)][ko];
            short8 a_l = *(const short8*)&Alo[w * 16 + (lane & 15)][ko];
#pragma unroll
            for (int n = 0; n < 4; n++) {
                short8 b_h = *(const short8*)&Bhi[n * 16 + (lane & 15)][ko];
                short8 b_l = *(const short8*)&Blo[n * 16 + (lane & 15)][ko];
                acc[n] = __builtin_amdgcn_mfma_f32_16x16x32_bf16(a_h, b_h, acc[n], 0, 0, 0);
                acc[n] = __builtin_amdgcn_mfma_f32_16x16x32_bf16(a_h, b_l, acc[n], 0, 0, 0);
                acc[n] = __builtin_amdgcn_mfma_f32_16x16x32_bf16(a_l, b_h, acc[n], 0, 0, 0);
            }
        }
        __syncthreads();
    }
    float* Mp = &M[(size_t)(j * SS_ + s) * 4096];
#pragma unroll
    for (int n = 0; n < 4; n++)
#pragma unroll
        for (int r = 0; r < 4; r++) {
            int c = w * 16 + (lane >> 4) * 4 + r;
            int dd = n * 16 + (lane & 15);
            Mp[c * 64 + dd] = acc[n][r];
        }
}

// K10: out[i][j][s][dd] = A + E. grid(128,5), block(256). M-column in VGPRs.
__global__ __launch_bounds__(256) void k_out(const float* __restrict__ M, const float* __restrict__ VC,
                      const float* __restrict__ sn, const float* __restrict__ rsd,
                      const float* __restrict__ tij, float* __restrict__ outb) {
    int j = blockIdx.x, s = blockIdx.y, t = threadIdx.x;
    int il = t >> 6, dd = t & 63;
    __shared__ float VCl[DI_];
    __shared__ float tl[4][64];
    __shared__ float snl[4][8];
    __shared__ float rl[4][8];
    float Mcol[64];
    const float* Mp = &M[(size_t)(j * SS_ + s) * 4096];
#pragma unroll
    for (int c = 0; c < 64; c++) Mcol[c] = Mp[c * 64 + dd];
    VCl[t] = VC[(j * SS_ + s) * DI_ + t];
    VCl[t + 256] = VC[(j * SS_ + s) * DI_ + t + 256];
    __syncthreads();
    for (int ib = 0; ib < NN; ib += 4) {
        int i = ib + il;
        tl[il][dd] = tij[(i * NN + j) * DD_ + dd];
        if (dd < 8) {
            snl[il][dd] = sn[i * 1024 + dd * NN + j];
            rl[il][dd] = rsd[i * 40 + dd * SS_ + s];
        }
        float A = 0.f;
#pragma unroll
        for (int hh = 0; hh < HH_; hh++) A += snl[il][hh] * rl[il][hh] * VCl[hh * DH_ + dd];
        float E = 0.f;
        const float4* tl4 = (const float4*)&tl[il][0];
#pragma unroll
        for (int c4 = 0; c4 < 16; c4++) {
            float4 tv = tl4[c4];
            E += tv.x * Mcol[4 * c4] + tv.y * Mcol[4 * c4 + 1] +
                 tv.z * Mcol[4 * c4 + 2] + tv.w * Mcol[4 * c4 + 3];
        }
        outb[((size_t)(i * NN + j) * SS_ + s) * 64 + dd] = A + E;
    }
}

// K11: final reductions over j + combine + fp32 store. grid(128), block(320).
__global__ void k_red(const float* __restrict__ outb, const float* __restrict__ h,
                      const float* __restrict__ r1, const float* __restrict__ r2,
                      const float* __restrict__ x1, const float* __restrict__ x2,
                      float* __restrict__ dst) {
    int i = blockIdx.x, t = threadIdx.x;
    int s = t >> 6, dd = t & 63;
    __shared__ float comb0[64 * 3], comb1[64 * 5];
    float hacc = 0.f;
    float am[5] = {0.f, 0.f, 0.f, 0.f, 0.f};
    for (int j = 0; j < NN; j++) {
        float ov = outb[((size_t)(i * NN + j) * SS_ + s) * 64 + dd];
        if (s == 0) {
            hacc += ov;
        } else if (s == 1) {
#pragma unroll
            for (int m = 0; m < 3; m++) am[m] += r1[(i * NN + j) * 3 + m] * ov;
        } else if (s == 2) {
#pragma unroll
            for (int m = 0; m < 5; m++) am[m] += r2[(i * NN + j) * 5 + m] * ov;
        } else if (s == 3) {
#pragma unroll
            for (int m = 0; m < 3; m++) am[m] += x1[(j * DD_ + dd) * 3 + m] * ov;
        } else {
#pragma unroll
            for (int m = 0; m < 5; m++) am[m] += x2[(j * DD_ + dd) * 5 + m] * ov;
        }
    }
    __syncthreads();
    if (s == 1) {
#pragma unroll
        for (int m = 0; m < 3; m++) comb0[dd * 3 + m] = am[m];
    } else if (s == 2) {
#pragma unroll
        for (int m = 0; m < 5; m++) comb1[dd * 5 + m] = am[m];
    }
    __syncthreads();
    if (s == 0) {
        dst[i * DD_ + dd] = h[i * DD_ + dd] + hacc;
    } else if (s == 3) {
#pragma unroll
        for (int m = 0; m < 3; m++)
            dst[8192 + (i * DD_ + dd) * 3 + m] = am[m] + comb0[dd * 3 + m];
    } else if (s == 4) {
#pragma unroll
        for (int m = 0; m < 5; m++)
            dst[8192 + 24576 + (i * DD_ + dd) * 5 + m] = am[m] + comb1[dd * 5 + m];
    }
}

extern "C" void kernel_launch(void* const* d_in, const int* in_sizes, int n_in,
                              void* d_out, int out_size, void* d_ws, size_t ws_size,
                              hipStream_t stream) {
    const float* h_in = (const float*)d_in[0];
    const float* tij = (const float*)d_in[1];
    const float* r1 = (const float*)d_in[2];
    const float* r2 = (const float*)d_in[3];
    const float* x1 = (const float*)d_in[4];
    const float* x2 = (const float*)d_in[5];
    const float* ghi = (const float*)d_in[6];
    const float* ghj = (const float*)d_in[7];
    const float* Wq = (const float*)d_in[8];
    const float* Wk = (const float*)d_in[9];
    const float* Wv1 = (const float*)d_in[10];
    const float* bv1 = (const float*)d_in[11];
    const float* Wv2 = (const float*)d_in[12];
    const float* bv2 = (const float*)d_in[13];
    const float* Wp1 = (const float*)d_in[14];
    const float* bp1 = (const float*)d_in[15];
    const float* Wp2 = (const float*)d_in[16];
    const float* bp2 = (const float*)d_in[17];
    const float* Wev = (const float*)d_in[18];
    const float* Wc = (const float*)d_in[19];
    float* dst = (float*)d_out;

    float* w = (float*)d_ws;
    size_t off = 16;
    auto alloc = [&](size_t n) { float* p = w + off; off += n; return p; };
    float* hi   = alloc(8192);
    float* hj   = alloc(8192);
    float* q    = alloc(65536);
    float* k    = alloc(65536);
    float* a1   = alloc(131072);
    float* p1   = alloc(131072);
    float* vals = alloc(327680);
    float* pav  = alloc(327680);
    float* VC   = alloc(327680);
    float* T    = alloc(8192);
    float* sn   = alloc(131072);
    float* EV   = alloc(327680);
    float* rsd  = alloc(5120);
    float* M    = alloc(2621440);
    float* outb = alloc(5242880);
    float* part = alloc(5242880);  // 8 x 655360 split-K partials

    k_ln<<<dim3(128), dim3(64), 0, stream>>>(h_in, ghi, ghj, hi, hj);
    k_qk<<<dim3(128), dim3(512), 0, stream>>>(hi, hj, Wq, Wk, q, k);
    k_mlp1<<<dim3(128, 2), dim3(256), 0, stream>>>(hj, Wv1, bv1, Wp1, bp1, a1, p1);
    k_mlp2<<<dim3(40, KSP), dim3(256), 0, stream>>>(a1, p1, Wv2, Wp2, part);
    k_mred<<<dim3(640), dim3(256), 0, stream>>>(part, bv2, bp2, vals, pav);
    k_vc<<<dim3(128, 5), dim3(512), 0, stream>>>(vals, Wc, VC);
    k_tsum<<<dim3(128), dim3(256), 0, stream>>>(tij, T);
    k_simnum<<<dim3(128, 8), dim3(128), 0, stream>>>(q, k, sn);
    k_evsum<<<dim3(128, 10), dim3(256), 0, stream>>>(T, Wev, EV);
    k_rsd<<<dim3(128, 10), dim3(256), 0, stream>>>(q, EV, rsd);
    k_M<<<dim3(128, 5), dim3(256), 0, stream>>>(pav, Wev, Wc, M);
    k_out<<<dim3(128, 5), dim3(256), 0, stream>>>(M, VC, sn, rsd, tij, outb);
    k_red<<<dim3(128), dim3(320), 0, stream>>>(outb, h_in, r1, r2, x1, x2, dst);
}

// Round 5
// 261.486 us; speedup vs baseline: 2.3378x; 1.2323x over previous
//
#include <hip/hip_runtime.h>
#include <hip/hip_bf16.h>

typedef __hip_bfloat16 bf16;
typedef __attribute__((ext_vector_type(8))) short short8;
typedef __attribute__((ext_vector_type(4))) float f32x4;

#define NN 128
#define DD_ 64
#define HH_ 8
#define DH_ 64
#define DI_ 512
#define SS_ 5
#define MLPD 1024
#define SDI 2560

__device__ __forceinline__ float wave_sum64(float v) {
#pragma unroll
    for (int off = 32; off > 0; off >>= 1) v += __shfl_xor(v, off, 64);
    return v;
}

__device__ __forceinline__ unsigned short f2bf_u(float f) {
    unsigned u = __float_as_uint(f);
    u += 0x7FFF + ((u >> 16) & 1);
    return (unsigned short)(u >> 16);
}
__device__ __forceinline__ float bfu2f(unsigned short s) {
    return __uint_as_float(((unsigned)s) << 16);
}
__device__ __forceinline__ unsigned pk2(unsigned short a, unsigned short b) {
    return (unsigned)a | ((unsigned)b << 16);
}

// K1: layernorm -> hi, hj. grid(128), block(64)
__global__ void k_ln(const float* __restrict__ h, const float* __restrict__ ghi,
                     const float* __restrict__ ghj, float* __restrict__ hi, float* __restrict__ hj) {
    int i = blockIdx.x, d = threadIdx.x;
    float x = h[i * DD_ + d];
    float s = wave_sum64(x);
    float s2 = wave_sum64(x * x);
    float m = s * (1.0f / DD_);
    float v = s2 * (1.0f / DD_) - m * m;
    float r = rsqrtf(v + 1e-5f);
    float xc = (x - m) * r;
    hi[i * DD_ + d] = xc * ghi[d];
    hj[i * DD_ + d] = xc * ghj[d];
}

// K2: q = hi@Wq, k = hj@Wk. grid(128), block(512)
__global__ void k_qk(const float* __restrict__ hi, const float* __restrict__ hj,
                     const float* __restrict__ Wq, const float* __restrict__ Wk,
                     float* __restrict__ q, float* __restrict__ k) {
    int i = blockIdx.x, t = threadIdx.x;
    __shared__ float hib[DD_], hjb[DD_];
    if (t < DD_) hib[t] = hi[i * DD_ + t];
    else if (t < 2 * DD_) hjb[t - DD_] = hj[i * DD_ + (t - DD_)];
    __syncthreads();
    float aq = 0.f, ak = 0.f;
#pragma unroll 8
    for (int d = 0; d < DD_; d++) {
        aq += hib[d] * Wq[d * DI_ + t];
        ak += hjb[d] * Wk[d * DI_ + t];
    }
    q[i * DI_ + t] = aq;
    k[i * DI_ + t] = ak;
}

// K3: a1 = silu(hj@Wv1+bv1), p1 = silu(hj@Wp1+bp1). grid(128,2), block(256)
__global__ void k_mlp1(const float* __restrict__ hj, const float* __restrict__ Wv1,
                       const float* __restrict__ bv1, const float* __restrict__ Wp1,
                       const float* __restrict__ bp1, float* __restrict__ a1, float* __restrict__ p1) {
    int j = blockIdx.x, t = threadIdx.x;
    const float* W = blockIdx.y ? Wp1 : Wv1;
    const float* b = blockIdx.y ? bp1 : bv1;
    float* dst = blockIdx.y ? p1 : a1;
    __shared__ float hb[DD_];
    if (t < DD_) hb[t] = hj[j * DD_ + t];
    __syncthreads();
    float acc[4] = {0.f, 0.f, 0.f, 0.f};
    for (int d = 0; d < DD_; d++) {
        float hv = hb[d];
#pragma unroll
        for (int r = 0; r < 4; r++) acc[r] += hv * W[d * MLPD + t + r * 256];
    }
#pragma unroll
    for (int r = 0; r < 4; r++) {
        float x = acc[r] + b[t + r * 256];
        dst[j * MLPD + t + r * 256] = x / (1.0f + expf(-x));
    }
}

// K4: split-K GEMM: part[ks][j][cc] = sum over k-slice of A[j,k]*W[k,cc]
#define KSP 8
#define KSL 128
__global__ __launch_bounds__(256) void k_mlp2(const float* __restrict__ a1,
                                              const float* __restrict__ p1,
                                              const float* __restrict__ Wv2,
                                              const float* __restrict__ Wp2,
                                              float* __restrict__ part) {
    int ct = blockIdx.x, ks = blockIdx.y, t = threadIdx.x;
    int c0 = ct * 128;
    bool isp = c0 >= 2560;
    int c0l = c0 - (isp ? 2560 : 0);
    const float* __restrict__ src = isp ? p1 : a1;
    const float* __restrict__ W = isp ? Wp2 : Wv2;
    int k0base = ks * KSL;
    __shared__ float As[128][33];
    __shared__ float Ws[32][128];
    int tc = t & 7;
    int tj = t >> 3;
    int j0 = tj * 4;
    float acc[4][16];
#pragma unroll
    for (int jj = 0; jj < 4; jj++)
#pragma unroll
        for (int cc = 0; cc < 16; cc++) acc[jj][cc] = 0.f;
    for (int kc = 0; kc < KSL; kc += 32) {
        int k0 = k0base + kc;
        __syncthreads();
#pragma unroll
        for (int it = 0; it < 4; it++) {
            int slot = t + it * 256;
            int jj = slot >> 3, f4 = (slot & 7) * 4;
            float4 v = *(const float4*)&src[jj * MLPD + k0 + f4];
            As[jj][f4 + 0] = v.x; As[jj][f4 + 1] = v.y;
            As[jj][f4 + 2] = v.z; As[jj][f4 + 3] = v.w;
        }
#pragma unroll
        for (int it = 0; it < 4; it++) {
            int slot = t + it * 256;
            int kk = slot >> 5, f4 = (slot & 31) * 4;
            float4 v = *(const float4*)&W[(size_t)(k0 + kk) * SDI + c0l + f4];
            *(float4*)&Ws[kk][f4] = v;
        }
        __syncthreads();
#pragma unroll 4
        for (int k = 0; k < 32; k++) {
            float a[4];
#pragma unroll
            for (int jj = 0; jj < 4; jj++) a[jj] = As[j0 + jj][k];
#pragma unroll
            for (int cf = 0; cf < 4; cf++) {
                float4 wv = *(const float4*)&Ws[k][tc * 4 + cf * 32];
#pragma unroll
                for (int jj = 0; jj < 4; jj++) {
                    acc[jj][cf * 4 + 0] += a[jj] * wv.x;
                    acc[jj][cf * 4 + 1] += a[jj] * wv.y;
                    acc[jj][cf * 4 + 2] += a[jj] * wv.z;
                    acc[jj][cf * 4 + 3] += a[jj] * wv.w;
                }
            }
        }
    }
#pragma unroll
    for (int jj = 0; jj < 4; jj++)
#pragma unroll
        for (int cf = 0; cf < 4; cf++) {
            float4 v = make_float4(acc[jj][cf * 4 + 0], acc[jj][cf * 4 + 1],
                                   acc[jj][cf * 4 + 2], acc[jj][cf * 4 + 3]);
            *(float4*)&part[(size_t)ks * 655360 + (size_t)(j0 + jj) * 5120 + c0 + tc * 4 + cf * 32] = v;
        }
}

// K4b: reduce 8 partials + bias -> vals / pav. grid(640), block(256)
__global__ void k_mred(const float* __restrict__ part, const float* __restrict__ bv2,
                       const float* __restrict__ bp2, float* __restrict__ vals,
                       float* __restrict__ pav) {
    int idx = blockIdx.x * 256 + threadIdx.x;
    int e0 = idx * 4;
    int j = e0 / 5120, cc = e0 % 5120;
    bool isp = cc >= 2560;
    int ccl = cc - (isp ? 2560 : 0);
    float sx = 0.f, sy = 0.f, sz = 0.f, sw = 0.f;
#pragma unroll
    for (int p = 0; p < KSP; p++) {
        float4 v = *(const float4*)&part[(size_t)p * 655360 + e0];
        sx += v.x; sy += v.y; sz += v.z; sw += v.w;
    }
    const float* b = isp ? bp2 : bv2;
    float4 bb = *(const float4*)&b[ccl];
    float* dst = isp ? pav : vals;
    *(float4*)&dst[(size_t)j * SDI + ccl] = make_float4(sx + bb.x, sy + bb.y, sz + bb.z, sw + bb.w);
}

// K5: VC[j][s][h][dd]. grid(128,5), block(512)
__global__ void k_vc(const float* __restrict__ vals, const float* __restrict__ Wc,
                     float* __restrict__ VC) {
    int j = blockIdx.x, s = blockIdx.y, t = threadIdx.x;
    int hh = t >> 6, dd = t & 63;
    __shared__ float vb[DI_];
    vb[t] = vals[j * SDI + s * DI_ + t];
    __syncthreads();
    float acc = 0.f;
#pragma unroll 8
    for (int d = 0; d < DH_; d++) acc += vb[hh * DH_ + d] * Wc[(hh * DH_ + d) * DD_ + dd];
    VC[((j * SS_ + s) * HH_ + hh) * DH_ + dd] = acc;
}

// K6: T[i][c] = sum_j t_ij[i,j,c]. grid(128), block(256)
__global__ void k_tsum(const float* __restrict__ tij, float* __restrict__ T) {
    int i = blockIdx.x, t = threadIdx.x;
    int c = t & 63, jw = t >> 6;
    float s = 0.f;
    for (int j = jw; j < NN; j += 4) s += tij[(i * NN + j) * DD_ + c];
    __shared__ float red[4][64];
    red[jw][c] = s;
    __syncthreads();
    if (t < 64) T[i * DD_ + t] = red[0][t] + red[1][t] + red[2][t] + red[3][t];
}

// K7: sn[i][h][j]. grid(128,8), block(128)
__global__ void k_simnum(const float* __restrict__ q, const float* __restrict__ k,
                         float* __restrict__ sn) {
    int i = blockIdx.x, hh = blockIdx.y, j = threadIdx.x;
    __shared__ float qb[DH_];
    if (j < DH_) qb[j] = q[i * DI_ + hh * DH_ + j];
    __syncthreads();
    float a = 0.f;
    const float* kr = &k[j * DI_ + hh * DH_];
#pragma unroll 8
    for (int d = 0; d < DH_; d++) a += qb[d] * kr[d];
    sn[i * 1024 + hh * NN + j] = a;
}

// K8a: EV[i][u]. grid(128,10), block(256)
__global__ void k_evsum(const float* __restrict__ T, const float* __restrict__ Wev,
                        float* __restrict__ EV) {
    int i = blockIdx.x, t = threadIdx.x;
    int u = blockIdx.y * 256 + t;
    __shared__ float Tb[DD_];
    if (t < DD_) Tb[t] = T[i * DD_ + t];
    __syncthreads();
    float a = 0.f;
#pragma unroll 8
    for (int c = 0; c < DD_; c++) a += Tb[c] * Wev[c * SDI + u];
    EV[i * SDI + u] = a;
}

// K8b: rsd[i][h][s]. grid(128,10), block(256)
__global__ void k_rsd(const float* __restrict__ q, const float* __restrict__ EV,
                      float* __restrict__ rsd) {
    int i = blockIdx.x, t = threadIdx.x;
    int wave = t >> 6, lane = t & 63;
    int p = blockIdx.y * 4 + wave;
    int hh = p / SS_, s = p % SS_;
    float v = q[i * DI_ + hh * DH_ + lane] * EV[i * SDI + s * DI_ + hh * DH_ + lane];
    v = wave_sum64(v);
    if (lane == 0) rsd[i * 40 + hh * SS_ + s] = 1.0f / v;
}

// K9: M via MFMA hi/lo bf16 compensation. grid(128,5), block(256)
#define KCM 64
__global__ __launch_bounds__(256) void k_M(const float* __restrict__ pav,
                                           const float* __restrict__ Wev,
                                           const float* __restrict__ Wc,
                                           float* __restrict__ M) {
    int j = blockIdx.x, s = blockIdx.y, t = threadIdx.x;
    int lane = t & 63, w = t >> 6;
    __shared__ float P[DI_];
    __shared__ unsigned short Ahi[64][72], Alo[64][72];
    __shared__ unsigned short Bhi[64][72], Blo[64][72];
    P[t] = pav[j * SDI + s * DI_ + t];
    P[t + 256] = pav[j * SDI + s * DI_ + t + 256];
    f32x4 acc[4];
#pragma unroll
    for (int n = 0; n < 4; n++) acc[n] = (f32x4){0.f, 0.f, 0.f, 0.f};
    __syncthreads();
    for (int u0 = 0; u0 < DI_; u0 += KCM) {
        {
            int c = t >> 2, ug = (t & 3) * 16;
            const float* wevp = &Wev[(size_t)c * SDI + s * DI_ + u0 + ug];
            unsigned short ah[16], al[16];
#pragma unroll
            for (int e = 0; e < 16; e += 4) {
                float4 wv = *(const float4*)(wevp + e);
                float4 pv = *(const float4*)&P[u0 + ug + e];
                float av[4] = {wv.x * pv.x, wv.y * pv.y, wv.z * pv.z, wv.w * pv.w};
#pragma unroll
                for (int z = 0; z < 4; z++) {
                    unsigned short hh2 = f2bf_u(av[z]);
                    ah[e + z] = hh2;
                    al[e + z] = f2bf_u(av[z] - bfu2f(hh2));
                }
            }
            *(uint4*)&Ahi[c][ug] = make_uint4(pk2(ah[0], ah[1]), pk2(ah[2], ah[3]),
                                              pk2(ah[4], ah[5]), pk2(ah[6], ah[7]));
            *(uint4*)&Ahi[c][ug + 8] = make_uint4(pk2(ah[8], ah[9]), pk2(ah[10], ah[11]),
                                                  pk2(ah[12], ah[13]), pk2(ah[14], ah[15]));
            *(uint4*)&Alo[c][ug] = make_uint4(pk2(al[0], al[1]), pk2(al[2], al[3]),
                                              pk2(al[4], al[5]), pk2(al[6], al[7]));
            *(uint4*)&Alo[c][ug + 8] = make_uint4(pk2(al[8], al[9]), pk2(al[10], al[11]),
                                                  pk2(al[12], al[13]), pk2(al[14], al[15]));
        }
        {
            int dd = t & 63, ub = (t >> 6) * 16;
            unsigned short bh[16], bl[16];
#pragma unroll
            for (int e = 0; e < 16; e++) {
                float v = Wc[(size_t)(u0 + ub + e) * DD_ + dd];
                unsigned short hh2 = f2bf_u(v);
                bh[e] = hh2;
                bl[e] = f2bf_u(v - bfu2f(hh2));
            }
            *(uint4*)&Bhi[dd][ub] = make_uint4(pk2(bh[0], bh[1]), pk2(bh[2], bh[3]),
                                               pk2(bh[4], bh[5]), pk2(bh[6], bh[7]));
            *(uint4*)&Bhi[dd][ub + 8] = make_uint4(pk2(bh[8], bh[9]), pk2(bh[10], bh[11]),
                                                   pk2(bh[12], bh[13]), pk2(bh[14], bh[15]));
            *(uint4*)&Blo[dd][ub] = make_uint4(pk2(bl[0], bl[1]), pk2(bl[2], bl[3]),
                                               pk2(bl[4], bl[5]), pk2(bl[6], bl[7]));
            *(uint4*)&Blo[dd][ub + 8] = make_uint4(pk2(bl[8], bl[9]), pk2(bl[10], bl[11]),
                                                   pk2(bl[12], bl[13]), pk2(bl[14], bl[15]));
        }
        __syncthreads();
#pragma unroll
        for (int kk = 0; kk < 2; kk++) {
            int ko = kk * 32 + (lane >> 4) * 8;
            short8 a_h = *(const short8*)&Ahi[w * 16 + (lane & 15)][ko];
            short8 a_l = *(const short8*)&Alo[w * 16 + (lane & 15)][ko];
#pragma unroll
            for (int n = 0; n < 4; n++) {
                short8 b_h = *(const short8*)&Bhi[n * 16 + (lane & 15)][ko];
                short8 b_l = *(const short8*)&Blo[n * 16 + (lane & 15)][ko];
                acc[n] = __builtin_amdgcn_mfma_f32_16x16x32_bf16(a_h, b_h, acc[n], 0, 0, 0);
                acc[n] = __builtin_amdgcn_mfma_f32_16x16x32_bf16(a_h, b_l, acc[n], 0, 0, 0);
                acc[n] = __builtin_amdgcn_mfma_f32_16x16x32_bf16(a_l, b_h, acc[n], 0, 0, 0);
            }
        }
        __syncthreads();
    }
    float* Mp = &M[(size_t)(j * SS_ + s) * 4096];
#pragma unroll
    for (int n = 0; n < 4; n++)
#pragma unroll
        for (int r = 0; r < 4; r++) {
            int c = w * 16 + (lane >> 4) * 4 + r;
            int dd = n * 16 + (lane & 15);
            Mp[c * 64 + dd] = acc[n][r];
        }
}

// K10: out[i][j][s][dd] = A + E. grid(128,5), block(256). M-column in VGPRs.
__global__ __launch_bounds__(256) void k_out(const float* __restrict__ M, const float* __restrict__ VC,
                      const float* __restrict__ sn, const float* __restrict__ rsd,
                      const float* __restrict__ tij, float* __restrict__ outb) {
    int j = blockIdx.x, s = blockIdx.y, t = threadIdx.x;
    int il = t >> 6, dd = t & 63;
    __shared__ float VCl[DI_];
    __shared__ float tl[4][64];
    __shared__ float snl[4][8];
    __shared__ float rl[4][8];
    float Mcol[64];
    const float* Mp = &M[(size_t)(j * SS_ + s) * 4096];
#pragma unroll
    for (int c = 0; c < 64; c++) Mcol[c] = Mp[c * 64 + dd];
    VCl[t] = VC[(j * SS_ + s) * DI_ + t];
    VCl[t + 256] = VC[(j * SS_ + s) * DI_ + t + 256];
    __syncthreads();
    for (int ib = 0; ib < NN; ib += 4) {
        int i = ib + il;
        tl[il][dd] = tij[(i * NN + j) * DD_ + dd];
        if (dd < 8) {
            snl[il][dd] = sn[i * 1024 + dd * NN + j];
            rl[il][dd] = rsd[i * 40 + dd * SS_ + s];
        }
        float A = 0.f;
#pragma unroll
        for (int hh = 0; hh < HH_; hh++) A += snl[il][hh] * rl[il][hh] * VCl[hh * DH_ + dd];
        float E = 0.f;
        const float4* tl4 = (const float4*)&tl[il][0];
#pragma unroll
        for (int c4 = 0; c4 < 16; c4++) {
            float4 tv = tl4[c4];
            E += tv.x * Mcol[4 * c4] + tv.y * Mcol[4 * c4 + 1] +
                 tv.z * Mcol[4 * c4 + 2] + tv.w * Mcol[4 * c4 + 3];
        }
        outb[((size_t)(i * NN + j) * SS_ + s) * 64 + dd] = A + E;
    }
}

// K11a: partial j-reduction. grid(128 i, 8 jc), block(320). 16 j per block.
// partial record (1088 floats): [0,64) h | [64,256) r1-part | [256,576) r2-part
//                               | [576,768) x1-part | [768,1088) x2-part
#define JC 8
#define JPC 16
__global__ void k_red1(const float* __restrict__ outb,
                       const float* __restrict__ r1, const float* __restrict__ r2,
                       const float* __restrict__ x1, const float* __restrict__ x2,
                       float* __restrict__ pr) {
    int i = blockIdx.x, jc = blockIdx.y, t = threadIdx.x;
    int s = t >> 6, dd = t & 63;
    int jbeg = jc * JPC;
    float hacc = 0.f;
    float am[5] = {0.f, 0.f, 0.f, 0.f, 0.f};
    for (int jj = 0; jj < JPC; jj++) {
        int j = jbeg + jj;
        float ov = outb[((size_t)(i * NN + j) * SS_ + s) * 64 + dd];
        if (s == 0) {
            hacc += ov;
        } else if (s == 1) {
#pragma unroll
            for (int m = 0; m < 3; m++) am[m] += r1[(i * NN + j) * 3 + m] * ov;
        } else if (s == 2) {
#pragma unroll
            for (int m = 0; m < 5; m++) am[m] += r2[(i * NN + j) * 5 + m] * ov;
        } else if (s == 3) {
#pragma unroll
            for (int m = 0; m < 3; m++) am[m] += x1[(j * DD_ + dd) * 3 + m] * ov;
        } else {
#pragma unroll
            for (int m = 0; m < 5; m++) am[m] += x2[(j * DD_ + dd) * 5 + m] * ov;
        }
    }
    float* rec = &pr[(size_t)(i * JC + jc) * 1088];
    if (s == 0) {
        rec[dd] = hacc;
    } else if (s == 1) {
#pragma unroll
        for (int m = 0; m < 3; m++) rec[64 + dd * 3 + m] = am[m];
    } else if (s == 2) {
#pragma unroll
        for (int m = 0; m < 5; m++) rec[256 + dd * 5 + m] = am[m];
    } else if (s == 3) {
#pragma unroll
        for (int m = 0; m < 3; m++) rec[576 + dd * 3 + m] = am[m];
    } else {
#pragma unroll
        for (int m = 0; m < 5; m++) rec[768 + dd * 5 + m] = am[m];
    }
}

// K11b: fold 8 partials + combine + store. grid(128), block(320).
__global__ void k_red2(const float* __restrict__ pr, const float* __restrict__ h,
                       float* __restrict__ dst) {
    int i = blockIdx.x, t = threadIdx.x;
    int s = t >> 6, dd = t & 63;
    const float* base = &pr[(size_t)i * JC * 1088];
    if (s == 0) {
        float v = 0.f;
#pragma unroll
        for (int c = 0; c < JC; c++) v += base[c * 1088 + dd];
        dst[i * DD_ + dd] = h[i * DD_ + dd] + v;
    } else if (s == 3) {
        float v[3] = {0.f, 0.f, 0.f};
#pragma unroll
        for (int c = 0; c < JC; c++) {
#pragma unroll
            for (int m = 0; m < 3; m++)
                v[m] += base[c * 1088 + 64 + dd * 3 + m] + base[c * 1088 + 576 + dd * 3 + m];
        }
#pragma unroll
        for (int m = 0; m < 3; m++)
            dst[8192 + (i * DD_ + dd) * 3 + m] = v[m];
    } else if (s == 4) {
        float v[5] = {0.f, 0.f, 0.f, 0.f, 0.f};
#pragma unroll
        for (int c = 0; c < JC; c++) {
#pragma unroll
            for (int m = 0; m < 5; m++)
                v[m] += base[c * 1088 + 256 + dd * 5 + m] + base[c * 1088 + 768 + dd * 5 + m];
        }
#pragma unroll
        for (int m = 0; m < 5; m++)
            dst[8192 + 24576 + (i * DD_ + dd) * 5 + m] = v[m];
    }
}

extern "C" void kernel_launch(void* const* d_in, const int* in_sizes, int n_in,
                              void* d_out, int out_size, void* d_ws, size_t ws_size,
                              hipStream_t stream) {
    const float* h_in = (const float*)d_in[0];
    const float* tij = (const float*)d_in[1];
    const float* r1 = (const float*)d_in[2];
    const float* r2 = (const float*)d_in[3];
    const float* x1 = (const float*)d_in[4];
    const float* x2 = (const float*)d_in[5];
    const float* ghi = (const float*)d_in[6];
    const float* ghj = (const float*)d_in[7];
    const float* Wq = (const float*)d_in[8];
    const float* Wk = (const float*)d_in[9];
    const float* Wv1 = (const float*)d_in[10];
    const float* bv1 = (const float*)d_in[11];
    const float* Wv2 = (const float*)d_in[12];
    const float* bv2 = (const float*)d_in[13];
    const float* Wp1 = (const float*)d_in[14];
    const float* bp1 = (const float*)d_in[15];
    const float* Wp2 = (const float*)d_in[16];
    const float* bp2 = (const float*)d_in[17];
    const float* Wev = (const float*)d_in[18];
    const float* Wc = (const float*)d_in[19];
    float* dst = (float*)d_out;

    float* w = (float*)d_ws;
    size_t off = 16;
    auto alloc = [&](size_t n) { float* p = w + off; off += n; return p; };
    float* hi   = alloc(8192);
    float* hj   = alloc(8192);
    float* q    = alloc(65536);
    float* k    = alloc(65536);
    float* a1   = alloc(131072);
    float* p1   = alloc(131072);
    float* vals = alloc(327680);
    float* pav  = alloc(327680);
    float* VC   = alloc(327680);
    float* T    = alloc(8192);
    float* sn   = alloc(131072);
    float* EV   = alloc(327680);
    float* rsd  = alloc(5120);
    float* M    = alloc(2621440);
    float* outb = alloc(5242880);
    float* part = alloc(5242880);  // 8 x 655360 split-K partials
    float* pr   = alloc(1114112);  // 128 x 8 x 1088 j-reduction partials

    k_ln<<<dim3(128), dim3(64), 0, stream>>>(h_in, ghi, ghj, hi, hj);
    k_qk<<<dim3(128), dim3(512), 0, stream>>>(hi, hj, Wq, Wk, q, k);
    k_mlp1<<<dim3(128, 2), dim3(256), 0, stream>>>(hj, Wv1, bv1, Wp1, bp1, a1, p1);
    k_mlp2<<<dim3(40, KSP), dim3(256), 0, stream>>>(a1, p1, Wv2, Wp2, part);
    k_mred<<<dim3(640), dim3(256), 0, stream>>>(part, bv2, bp2, vals, pav);
    k_vc<<<dim3(128, 5), dim3(512), 0, stream>>>(vals, Wc, VC);
    k_tsum<<<dim3(128), dim3(256), 0, stream>>>(tij, T);
    k_simnum<<<dim3(128, 8), dim3(128), 0, stream>>>(q, k, sn);
    k_evsum<<<dim3(128, 10), dim3(256), 0, stream>>>(T, Wev, EV);
    k_rsd<<<dim3(128, 10), dim3(256), 0, stream>>>(q, EV, rsd);
    k_M<<<dim3(128, 5), dim3(256), 0, stream>>>(pav, Wev, Wc, M);
    k_out<<<dim3(128, 5), dim3(256), 0, stream>>>(M, VC, sn, rsd, tij, outb);
    k_red1<<<dim3(128, JC), dim3(320), 0, stream>>>(outb, r1, r2, x1, x2, pr);
    k_red2<<<dim3(128), dim3(320), 0, stream>>>(pr, h_in, dst);
}

// Round 6
// 259.047 us; speedup vs baseline: 2.3599x; 1.0094x over previous
//
#include <hip/hip_runtime.h>
#include <hip/hip_bf16.h>

typedef __hip_bfloat16 bf16;
typedef __attribute__((ext_vector_type(8))) short short8;
typedef __attribute__((ext_vector_type(4))) float f32x4;

#define NN 128
#define DD_ 64
#define HH_ 8
#define DH_ 64
#define DI_ 512
#define SS_ 5
#define MLPD 1024
#define SDI 2560

__device__ __forceinline__ float wave_sum64(float v) {
#pragma unroll
    for (int off = 32; off > 0; off >>= 1) v += __shfl_xor(v, off, 64);
    return v;
}

__device__ __forceinline__ unsigned short f2bf_u(float f) {
    unsigned u = __float_as_uint(f);
    u += 0x7FFF + ((u >> 16) & 1);
    return (unsigned short)(u >> 16);
}
__device__ __forceinline__ float bfu2f(unsigned short s) {
    return __uint_as_float(((unsigned)s) << 16);
}
__device__ __forceinline__ unsigned pk2(unsigned short a, unsigned short b) {
    return (unsigned)a | ((unsigned)b << 16);
}

// K1: fused layernorm + q/k projection + MLP1. grid(128 nodes), block(512).
// hi/hj live only in LDS; writes q, k, a1, p1.
__global__ __launch_bounds__(512) void k_front(
    const float* __restrict__ h, const float* __restrict__ ghi, const float* __restrict__ ghj,
    const float* __restrict__ Wq, const float* __restrict__ Wk,
    const float* __restrict__ Wv1, const float* __restrict__ bv1,
    const float* __restrict__ Wp1, const float* __restrict__ bp1,
    float* __restrict__ q, float* __restrict__ k,
    float* __restrict__ a1, float* __restrict__ p1) {
    int i = blockIdx.x, t = threadIdx.x;
    int d = t & 63;
    __shared__ float hib[DD_], hjb[DD_];
    // every wave holds the full 64-elem row -> redundant identical reductions, benign
    float x = h[i * DD_ + d];
    float s = wave_sum64(x);
    float s2 = wave_sum64(x * x);
    float m = s * (1.0f / DD_);
    float v = s2 * (1.0f / DD_) - m * m;
    float r = rsqrtf(v + 1e-5f);
    float xc = (x - m) * r;
    hib[d] = xc * ghi[d];   // all 8 waves write identical values
    hjb[d] = xc * ghj[d];
    __syncthreads();
    // q/k: 512 cols
    float aq = 0.f, ak = 0.f;
#pragma unroll 8
    for (int dd = 0; dd < DD_; dd++) {
        aq += hib[dd] * Wq[dd * DI_ + t];
        ak += hjb[dd] * Wk[dd * DI_ + t];
    }
    q[i * DI_ + t] = aq;
    k[i * DI_ + t] = ak;
    // mlp1: 1024 cols each for v and p -> 2 cols per thread per matrix
    float av0 = 0.f, av1 = 0.f, ap0 = 0.f, ap1_ = 0.f;
    for (int dd = 0; dd < DD_; dd++) {
        float hv = hjb[dd];
        av0 += hv * Wv1[dd * MLPD + t];
        av1 += hv * Wv1[dd * MLPD + t + 512];
        ap0 += hv * Wp1[dd * MLPD + t];
        ap1_ += hv * Wp1[dd * MLPD + t + 512];
    }
    float x0 = av0 + bv1[t];
    float x1v = av1 + bv1[t + 512];
    float y0 = ap0 + bp1[t];
    float y1 = ap1_ + bp1[t + 512];
    a1[i * MLPD + t] = x0 / (1.0f + expf(-x0));
    a1[i * MLPD + t + 512] = x1v / (1.0f + expf(-x1v));
    p1[i * MLPD + t] = y0 / (1.0f + expf(-y0));
    p1[i * MLPD + t + 512] = y1 / (1.0f + expf(-y1));
}

// K4: split-K GEMM: part[ks][j][cc] = sum over k-slice of A[j,k]*W[k,cc]
#define KSP 8
#define KSL 128
__global__ __launch_bounds__(256) void k_mlp2(const float* __restrict__ a1,
                                              const float* __restrict__ p1,
                                              const float* __restrict__ Wv2,
                                              const float* __restrict__ Wp2,
                                              float* __restrict__ part) {
    int ct = blockIdx.x, ks = blockIdx.y, t = threadIdx.x;
    int c0 = ct * 128;
    bool isp = c0 >= 2560;
    int c0l = c0 - (isp ? 2560 : 0);
    const float* __restrict__ src = isp ? p1 : a1;
    const float* __restrict__ W = isp ? Wp2 : Wv2;
    int k0base = ks * KSL;
    __shared__ float As[128][33];
    __shared__ float Ws[32][128];
    int tc = t & 7;
    int tj = t >> 3;
    int j0 = tj * 4;
    float acc[4][16];
#pragma unroll
    for (int jj = 0; jj < 4; jj++)
#pragma unroll
        for (int cc = 0; cc < 16; cc++) acc[jj][cc] = 0.f;
    for (int kc = 0; kc < KSL; kc += 32) {
        int k0 = k0base + kc;
        __syncthreads();
#pragma unroll
        for (int it = 0; it < 4; it++) {
            int slot = t + it * 256;
            int jj = slot >> 3, f4 = (slot & 7) * 4;
            float4 v = *(const float4*)&src[jj * MLPD + k0 + f4];
            As[jj][f4 + 0] = v.x; As[jj][f4 + 1] = v.y;
            As[jj][f4 + 2] = v.z; As[jj][f4 + 3] = v.w;
        }
#pragma unroll
        for (int it = 0; it < 4; it++) {
            int slot = t + it * 256;
            int kk = slot >> 5, f4 = (slot & 31) * 4;
            float4 v = *(const float4*)&W[(size_t)(k0 + kk) * SDI + c0l + f4];
            *(float4*)&Ws[kk][f4] = v;
        }
        __syncthreads();
#pragma unroll 4
        for (int kx = 0; kx < 32; kx++) {
            float a[4];
#pragma unroll
            for (int jj = 0; jj < 4; jj++) a[jj] = As[j0 + jj][kx];
#pragma unroll
            for (int cf = 0; cf < 4; cf++) {
                float4 wv = *(const float4*)&Ws[kx][tc * 4 + cf * 32];
#pragma unroll
                for (int jj = 0; jj < 4; jj++) {
                    acc[jj][cf * 4 + 0] += a[jj] * wv.x;
                    acc[jj][cf * 4 + 1] += a[jj] * wv.y;
                    acc[jj][cf * 4 + 2] += a[jj] * wv.z;
                    acc[jj][cf * 4 + 3] += a[jj] * wv.w;
                }
            }
        }
    }
#pragma unroll
    for (int jj = 0; jj < 4; jj++)
#pragma unroll
        for (int cf = 0; cf < 4; cf++) {
            float4 v = make_float4(acc[jj][cf * 4 + 0], acc[jj][cf * 4 + 1],
                                   acc[jj][cf * 4 + 2], acc[jj][cf * 4 + 3]);
            *(float4*)&part[(size_t)ks * 655360 + (size_t)(j0 + jj) * 5120 + c0 + tc * 4 + cf * 32] = v;
        }
}

// K4b fused with K5: reduce partials + bias -> pav (global) + vals (LDS) -> VC.
// grid(128 j), block(512).
__global__ __launch_bounds__(512) void k_post(const float* __restrict__ part,
                                              const float* __restrict__ bv2,
                                              const float* __restrict__ bp2,
                                              const float* __restrict__ Wc,
                                              float* __restrict__ pav,
                                              float* __restrict__ VC) {
    int j = blockIdx.x, t = threadIdx.x;
    __shared__ float vlds[SDI];
#pragma unroll
    for (int kx = 0; kx < 10; kx++) {
        int e = t + kx * 512;  // e in [0,5120)
        float s = 0.f;
#pragma unroll
        for (int p = 0; p < KSP; p++) s += part[(size_t)p * 655360 + (size_t)j * 5120 + e];
        if (e < 2560) {
            vlds[e] = s + bv2[e];
        } else {
            pav[(size_t)j * SDI + (e - 2560)] = s + bp2[e - 2560];
        }
    }
    __syncthreads();
#pragma unroll
    for (int kx = 0; kx < 5; kx++) {
        int o = t + kx * 512;       // o in [0,2560)
        int dd = o & 63;
        int base = o - dd;          // s*512 + h*64
        int rem = o & 511;
        int hbase = rem - dd;       // h*64
        float acc = 0.f;
#pragma unroll 8
        for (int d = 0; d < DH_; d++)
            acc += vlds[base + d] * Wc[(size_t)(hbase + d) * DD_ + dd];
        VC[(size_t)(j * SS_) * DI_ + o] = acc;  // layout [(j*5+s)*512 + h*64+dd]
    }
}

// K6+K8: fused T-sum, EV, rsd. grid(128 i), block(640).
__global__ __launch_bounds__(640) void k_den(const float* __restrict__ tij,
                                             const float* __restrict__ Wev,
                                             const float* __restrict__ q,
                                             float* __restrict__ rsd) {
    int i = blockIdx.x, t = threadIdx.x;
    __shared__ float red[10][64];
    __shared__ float Tl[64];
    __shared__ float ql[DI_];
    int c = t & 63, jw = t >> 6;
    float s = 0.f;
    for (int j = jw; j < NN; j += 10) s += tij[(size_t)(i * NN + j) * DD_ + c];
    red[jw][c] = s;
    if (t < DI_) ql[t] = q[i * DI_ + t];
    __syncthreads();
    if (t < 64) {
        float a = 0.f;
#pragma unroll
        for (int r = 0; r < 10; r++) a += red[r][t];
        Tl[t] = a;
    }
    __syncthreads();
#pragma unroll
    for (int kx = 0; kx < 4; kx++) {
        int u = kx * 640 + t;  // u in [0,2560)
        float ev = 0.f;
#pragma unroll 8
        for (int cc = 0; cc < DD_; cc++) ev += Tl[cc] * Wev[(size_t)cc * SDI + u];
        float prod = ev * ql[u & 511];
        float den = wave_sum64(prod);
        if ((t & 63) == 0) {
            int g = u >> 6;           // = k*10 + wave, in [0,40)
            int ss = g >> 3, hh = g & 7;
            rsd[i * 40 + hh * SS_ + ss] = 1.0f / den;
        }
    }
}

// K7: sn[i][h][j]. grid(128), block(1024).
__global__ __launch_bounds__(1024) void k_simnum(const float* __restrict__ q,
                                                 const float* __restrict__ k,
                                                 float* __restrict__ sn) {
    int i = blockIdx.x, t = threadIdx.x;
    int hh = t >> 7, j = t & 127;
    __shared__ float qb[DI_];
    if (t < DI_) qb[t] = q[i * DI_ + t];
    __syncthreads();
    float a = 0.f;
    const float* kr = &k[(size_t)j * DI_ + hh * DH_];
    const float* qr = &qb[hh * DH_];
#pragma unroll 8
    for (int d = 0; d < DH_; d++) a += qr[d] * kr[d];
    sn[i * 1024 + hh * NN + j] = a;
}

// K9: M via MFMA hi/lo bf16 compensation. grid(128,5), block(256)
#define KCM 64
__global__ __launch_bounds__(256) void k_M(const float* __restrict__ pav,
                                           const float* __restrict__ Wev,
                                           const float* __restrict__ Wc,
                                           float* __restrict__ M) {
    int j = blockIdx.x, s = blockIdx.y, t = threadIdx.x;
    int lane = t & 63, w = t >> 6;
    __shared__ float P[DI_];
    __shared__ unsigned short Ahi[64][72], Alo[64][72];
    __shared__ unsigned short Bhi[64][72], Blo[64][72];
    P[t] = pav[j * SDI + s * DI_ + t];
    P[t + 256] = pav[j * SDI + s * DI_ + t + 256];
    f32x4 acc[4];
#pragma unroll
    for (int n = 0; n < 4; n++) acc[n] = (f32x4){0.f, 0.f, 0.f, 0.f};
    __syncthreads();
    for (int u0 = 0; u0 < DI_; u0 += KCM) {
        {
            int c = t >> 2, ug = (t & 3) * 16;
            const float* wevp = &Wev[(size_t)c * SDI + s * DI_ + u0 + ug];
            unsigned short ah[16], al[16];
#pragma unroll
            for (int e = 0; e < 16; e += 4) {
                float4 wv = *(const float4*)(wevp + e);
                float4 pv = *(const float4*)&P[u0 + ug + e];
                float av[4] = {wv.x * pv.x, wv.y * pv.y, wv.z * pv.z, wv.w * pv.w};
#pragma unroll
                for (int z = 0; z < 4; z++) {
                    unsigned short hh2 = f2bf_u(av[z]);
                    ah[e + z] = hh2;
                    al[e + z] = f2bf_u(av[z] - bfu2f(hh2));
                }
            }
            *(uint4*)&Ahi[c][ug] = make_uint4(pk2(ah[0], ah[1]), pk2(ah[2], ah[3]),
                                              pk2(ah[4], ah[5]), pk2(ah[6], ah[7]));
            *(uint4*)&Ahi[c][ug + 8] = make_uint4(pk2(ah[8], ah[9]), pk2(ah[10], ah[11]),
                                                  pk2(ah[12], ah[13]), pk2(ah[14], ah[15]));
            *(uint4*)&Alo[c][ug] = make_uint4(pk2(al[0], al[1]), pk2(al[2], al[3]),
                                              pk2(al[4], al[5]), pk2(al[6], al[7]));
            *(uint4*)&Alo[c][ug + 8] = make_uint4(pk2(al[8], al[9]), pk2(al[10], al[11]),
                                                  pk2(al[12], al[13]), pk2(al[14], al[15]));
        }
        {
            int dd = t & 63, ub = (t >> 6) * 16;
            unsigned short bh[16], bl[16];
#pragma unroll
            for (int e = 0; e < 16; e++) {
                float v = Wc[(size_t)(u0 + ub + e) * DD_ + dd];
                unsigned short hh2 = f2bf_u(v);
                bh[e] = hh2;
                bl[e] = f2bf_u(v - bfu2f(hh2));
            }
            *(uint4*)&Bhi[dd][ub] = make_uint4(pk2(bh[0], bh[1]), pk2(bh[2], bh[3]),
                                               pk2(bh[4], bh[5]), pk2(bh[6], bh[7]));
            *(uint4*)&Bhi[dd][ub + 8] = make_uint4(pk2(bh[8], bh[9]), pk2(bh[10], bh[11]),
                                                   pk2(bh[12], bh[13]), pk2(bh[14], bh[15]));
            *(uint4*)&Blo[dd][ub] = make_uint4(pk2(bl[0], bl[1]), pk2(bl[2], bl[3]),
                                               pk2(bl[4], bl[5]), pk2(bl[6], bl[7]));
            *(uint4*)&Blo[dd][ub + 8] = make_uint4(pk2(bl[8], bl[9]), pk2(bl[10], bl[11]),
                                                   pk2(bl[12], bl[13]), pk2(bl[14], bl[15]));
        }
        __syncthreads();
#pragma unroll
        for (int kk = 0; kk < 2; kk++) {
            int ko = kk * 32 + (lane >> 4) * 8;
            short8 a_h = *(const short8*)&Ahi[w * 16 + (lane & 15)][ko];
            short8 a_l = *(const short8*)&Alo[w * 16 + (lane & 15)][ko];
#pragma unroll
            for (int n = 0; n < 4; n++) {
                short8 b_h = *(const short8*)&Bhi[n * 16 + (lane & 15)][ko];
                short8 b_l = *(const short8*)&Blo[n * 16 + (lane & 15)][ko];
                acc[n] = __builtin_amdgcn_mfma_f32_16x16x32_bf16(a_h, b_h, acc[n], 0, 0, 0);
                acc[n] = __builtin_amdgcn_mfma_f32_16x16x32_bf16(a_h, b_l, acc[n], 0, 0, 0);
                acc[n] = __builtin_amdgcn_mfma_f32_16x16x32_bf16(a_l, b_h, acc[n], 0, 0, 0);
            }
        }
        __syncthreads();
    }
    float* Mp = &M[(size_t)(j * SS_ + s) * 4096];
#pragma unroll
    for (int n = 0; n < 4; n++)
#pragma unroll
        for (int r = 0; r < 4; r++) {
            int c = w * 16 + (lane >> 4) * 4 + r;
            int dd = n * 16 + (lane & 15);
            Mp[c * 64 + dd] = acc[n][r];
        }
}

// K10: out[i][j][s][dd] = A + E. grid(128,5), block(256). M-column in VGPRs.
__global__ __launch_bounds__(256) void k_out(const float* __restrict__ M, const float* __restrict__ VC,
                      const float* __restrict__ sn, const float* __restrict__ rsd,
                      const float* __restrict__ tij, float* __restrict__ outb) {
    int j = blockIdx.x, s = blockIdx.y, t = threadIdx.x;
    int il = t >> 6, dd = t & 63;
    __shared__ float VCl[DI_];
    __shared__ float tl[4][64];
    __shared__ float snl[4][8];
    __shared__ float rl[4][8];
    float Mcol[64];
    const float* Mp = &M[(size_t)(j * SS_ + s) * 4096];
#pragma unroll
    for (int c = 0; c < 64; c++) Mcol[c] = Mp[c * 64 + dd];
    VCl[t] = VC[(j * SS_ + s) * DI_ + t];
    VCl[t + 256] = VC[(j * SS_ + s) * DI_ + t + 256];
    __syncthreads();
    for (int ib = 0; ib < NN; ib += 4) {
        int i = ib + il;
        tl[il][dd] = tij[(size_t)(i * NN + j) * DD_ + dd];
        if (dd < 8) {
            snl[il][dd] = sn[i * 1024 + dd * NN + j];
            rl[il][dd] = rsd[i * 40 + dd * SS_ + s];
        }
        float A = 0.f;
#pragma unroll
        for (int hh = 0; hh < HH_; hh++) A += snl[il][hh] * rl[il][hh] * VCl[hh * DH_ + dd];
        float E = 0.f;
        const float4* tl4 = (const float4*)&tl[il][0];
#pragma unroll
        for (int c4 = 0; c4 < 16; c4++) {
            float4 tv = tl4[c4];
            E += tv.x * Mcol[4 * c4] + tv.y * Mcol[4 * c4 + 1] +
                 tv.z * Mcol[4 * c4 + 2] + tv.w * Mcol[4 * c4 + 3];
        }
        outb[((size_t)(i * NN + j) * SS_ + s) * 64 + dd] = A + E;
    }
}

// K11a: partial j-reduction. grid(128 i, 8 jc), block(320). 16 j per block.
#define JC 8
#define JPC 16
__global__ void k_red1(const float* __restrict__ outb,
                       const float* __restrict__ r1, const float* __restrict__ r2,
                       const float* __restrict__ x1, const float* __restrict__ x2,
                       float* __restrict__ pr) {
    int i = blockIdx.x, jc = blockIdx.y, t = threadIdx.x;
    int s = t >> 6, dd = t & 63;
    int jbeg = jc * JPC;
    float hacc = 0.f;
    float am[5] = {0.f, 0.f, 0.f, 0.f, 0.f};
    for (int jj = 0; jj < JPC; jj++) {
        int j = jbeg + jj;
        float ov = outb[((size_t)(i * NN + j) * SS_ + s) * 64 + dd];
        if (s == 0) {
            hacc += ov;
        } else if (s == 1) {
#pragma unroll
            for (int m = 0; m < 3; m++) am[m] += r1[(i * NN + j) * 3 + m] * ov;
        } else if (s == 2) {
#pragma unroll
            for (int m = 0; m < 5; m++) am[m] += r2[(i * NN + j) * 5 + m] * ov;
        } else if (s == 3) {
#pragma unroll
            for (int m = 0; m < 3; m++) am[m] += x1[(j * DD_ + dd) * 3 + m] * ov;
        } else {
#pragma unroll
            for (int m = 0; m < 5; m++) am[m] += x2[(j * DD_ + dd) * 5 + m] * ov;
        }
    }
    float* rec = &pr[(size_t)(i * JC + jc) * 1088];
    if (s == 0) {
        rec[dd] = hacc;
    } else if (s == 1) {
#pragma unroll
        for (int m = 0; m < 3; m++) rec[64 + dd * 3 + m] = am[m];
    } else if (s == 2) {
#pragma unroll
        for (int m = 0; m < 5; m++) rec[256 + dd * 5 + m] = am[m];
    } else if (s == 3) {
#pragma unroll
        for (int m = 0; m < 3; m++) rec[576 + dd * 3 + m] = am[m];
    } else {
#pragma unroll
        for (int m = 0; m < 5; m++) rec[768 + dd * 5 + m] = am[m];
    }
}

// K11b: fold 8 partials + combine + store. grid(128), block(320).
__global__ void k_red2(const float* __restrict__ pr, const float* __restrict__ h,
                       float* __restrict__ dst) {
    int i = blockIdx.x, t = threadIdx.x;
    int s = t >> 6, dd = t & 63;
    const float* base = &pr[(size_t)i * JC * 1088];
    if (s == 0) {
        float v = 0.f;
#pragma unroll
        for (int c = 0; c < JC; c++) v += base[c * 1088 + dd];
        dst[i * DD_ + dd] = h[i * DD_ + dd] + v;
    } else if (s == 3) {
        float v[3] = {0.f, 0.f, 0.f};
#pragma unroll
        for (int c = 0; c < JC; c++) {
#pragma unroll
            for (int m = 0; m < 3; m++)
                v[m] += base[c * 1088 + 64 + dd * 3 + m] + base[c * 1088 + 576 + dd * 3 + m];
        }
#pragma unroll
        for (int m = 0; m < 3; m++)
            dst[8192 + (i * DD_ + dd) * 3 + m] = v[m];
    } else if (s == 4) {
        float v[5] = {0.f, 0.f, 0.f, 0.f, 0.f};
#pragma unroll
        for (int c = 0; c < JC; c++) {
#pragma unroll
            for (int m = 0; m < 5; m++)
                v[m] += base[c * 1088 + 256 + dd * 5 + m] + base[c * 1088 + 768 + dd * 5 + m];
        }
#pragma unroll
        for (int m = 0; m < 5; m++)
            dst[8192 + 24576 + (i * DD_ + dd) * 5 + m] = v[m];
    }
}

extern "C" void kernel_launch(void* const* d_in, const int* in_sizes, int n_in,
                              void* d_out, int out_size, void* d_ws, size_t ws_size,
                              hipStream_t stream) {
    const float* h_in = (const float*)d_in[0];
    const float* tij = (const float*)d_in[1];
    const float* r1 = (const float*)d_in[2];
    const float* r2 = (const float*)d_in[3];
    const float* x1 = (const float*)d_in[4];
    const float* x2 = (const float*)d_in[5];
    const float* ghi = (const float*)d_in[6];
    const float* ghj = (const float*)d_in[7];
    const float* Wq = (const float*)d_in[8];
    const float* Wk = (const float*)d_in[9];
    const float* Wv1 = (const float*)d_in[10];
    const float* bv1 = (const float*)d_in[11];
    const float* Wv2 = (const float*)d_in[12];
    const float* bv2 = (const float*)d_in[13];
    const float* Wp1 = (const float*)d_in[14];
    const float* bp1 = (const float*)d_in[15];
    const float* Wp2 = (const float*)d_in[16];
    const float* bp2 = (const float*)d_in[17];
    const float* Wev = (const float*)d_in[18];
    const float* Wc = (const float*)d_in[19];
    float* dst = (float*)d_out;

    float* w = (float*)d_ws;
    size_t off = 16;
    auto alloc = [&](size_t n) { float* p = w + off; off += n; return p; };
    float* q    = alloc(65536);
    float* k    = alloc(65536);
    float* a1   = alloc(131072);
    float* p1   = alloc(131072);
    float* pav  = alloc(327680);
    float* VC   = alloc(327680);
    float* sn   = alloc(131072);
    float* rsd  = alloc(5120);
    float* M    = alloc(2621440);
    float* outb = alloc(5242880);
    float* part = alloc(5242880);  // 8 x 655360 split-K partials
    float* pr   = alloc(1114112);  // 128 x 8 x 1088 j-reduction partials

    k_front<<<dim3(128), dim3(512), 0, stream>>>(h_in, ghi, ghj, Wq, Wk, Wv1, bv1, Wp1, bp1,
                                                 q, k, a1, p1);
    k_mlp2<<<dim3(40, KSP), dim3(256), 0, stream>>>(a1, p1, Wv2, Wp2, part);
    k_post<<<dim3(128), dim3(512), 0, stream>>>(part, bv2, bp2, Wc, pav, VC);
    k_den<<<dim3(128), dim3(640), 0, stream>>>(tij, Wev, q, rsd);
    k_simnum<<<dim3(128), dim3(1024), 0, stream>>>(q, k, sn);
    k_M<<<dim3(128, 5), dim3(256), 0, stream>>>(pav, Wev, Wc, M);
    k_out<<<dim3(128, 5), dim3(256), 0, stream>>>(M, VC, sn, rsd, tij, outb);
    k_red1<<<dim3(128, JC), dim3(320), 0, stream>>>(outb, r1, r2, x1, x2, pr);
    k_red2<<<dim3(128), dim3(320), 0, stream>>>(pr, h_in, dst);
}

// Round 7
// 244.399 us; speedup vs baseline: 2.5013x; 1.0599x over previous
//
#include <hip/hip_runtime.h>
#include <hip/hip_bf16.h>

typedef __hip_bfloat16 bf16;
typedef __attribute__((ext_vector_type(8))) short short8;
typedef __attribute__((ext_vector_type(4))) float f32x4;

#define NN 128
#define DD_ 64
#define HH_ 8
#define DH_ 64
#define DI_ 512
#define SS_ 5
#define MLPD 1024
#define SDI 2560

__device__ __forceinline__ float wave_sum64(float v) {
#pragma unroll
    for (int off = 32; off > 0; off >>= 1) v += __shfl_xor(v, off, 64);
    return v;
}

__device__ __forceinline__ unsigned short f2bf_u(float f) {
    unsigned u = __float_as_uint(f);
    u += 0x7FFF + ((u >> 16) & 1);
    return (unsigned short)(u >> 16);
}
__device__ __forceinline__ float bfu2f(unsigned short s) {
    return __uint_as_float(((unsigned)s) << 16);
}
__device__ __forceinline__ unsigned pk2(unsigned short a, unsigned short b) {
    return (unsigned)a | ((unsigned)b << 16);
}

// K1: fused LN + q/k + mlp1, column-chunked. grid(128 i, 4 ch), block(256).
__global__ __launch_bounds__(256) void k_front(
    const float* __restrict__ h, const float* __restrict__ ghi, const float* __restrict__ ghj,
    const float* __restrict__ Wq, const float* __restrict__ Wk,
    const float* __restrict__ Wv1, const float* __restrict__ bv1,
    const float* __restrict__ Wp1, const float* __restrict__ bp1,
    float* __restrict__ q, float* __restrict__ k,
    float* __restrict__ a1, float* __restrict__ p1) {
    int i = blockIdx.x, ch = blockIdx.y, t = threadIdx.x;
    int d = t & 63;
    __shared__ float hib[DD_], hjb[DD_];
    float x = h[i * DD_ + d];
    float s = wave_sum64(x);
    float s2 = wave_sum64(x * x);
    float m = s * (1.0f / DD_);
    float v = s2 * (1.0f / DD_) - m * m;
    float r = rsqrtf(v + 1e-5f);
    float xc = (x - m) * r;
    if (t < 64) { hib[d] = xc * ghi[d]; hjb[d] = xc * ghj[d]; }
    __syncthreads();
    // q (t<128) / k (t>=128): col = ch*128 + (t&127)
    {
        int c = ch * 128 + (t & 127);
        const float* W = (t < 128) ? Wq : Wk;
        const float* hb = (t < 128) ? hib : hjb;
        float a = 0.f;
#pragma unroll 8
        for (int dd = 0; dd < DD_; dd++) a += hb[dd] * W[dd * DI_ + c];
        float* dstqk = (t < 128) ? q : k;
        dstqk[i * DI_ + c] = a;
    }
    // mlp1: col = ch*256 + t for both matrices
    {
        int c = ch * 256 + t;
        float av = 0.f, ap = 0.f;
#pragma unroll 4
        for (int dd = 0; dd < DD_; dd++) {
            float hv = hjb[dd];
            av += hv * Wv1[dd * MLPD + c];
            ap += hv * Wp1[dd * MLPD + c];
        }
        float xv = av + bv1[c], xp = ap + bp1[c];
        a1[i * MLPD + c] = xv / (1.0f + expf(-xv));
        p1[i * MLPD + c] = xp / (1.0f + expf(-xp));
    }
}

// K4: split-K GEMM. grid(40, 8), block(256).
#define KSP 8
#define KSL 128
__global__ __launch_bounds__(256) void k_mlp2(const float* __restrict__ a1,
                                              const float* __restrict__ p1,
                                              const float* __restrict__ Wv2,
                                              const float* __restrict__ Wp2,
                                              float* __restrict__ part) {
    int ct = blockIdx.x, ks = blockIdx.y, t = threadIdx.x;
    int c0 = ct * 128;
    bool isp = c0 >= 2560;
    int c0l = c0 - (isp ? 2560 : 0);
    const float* __restrict__ src = isp ? p1 : a1;
    const float* __restrict__ W = isp ? Wp2 : Wv2;
    int k0base = ks * KSL;
    __shared__ float As[128][33];
    __shared__ float Ws[32][128];
    int tc = t & 7;
    int tj = t >> 3;
    int j0 = tj * 4;
    float acc[4][16];
#pragma unroll
    for (int jj = 0; jj < 4; jj++)
#pragma unroll
        for (int cc = 0; cc < 16; cc++) acc[jj][cc] = 0.f;
    for (int kc = 0; kc < KSL; kc += 32) {
        int k0 = k0base + kc;
        __syncthreads();
#pragma unroll
        for (int it = 0; it < 4; it++) {
            int slot = t + it * 256;
            int jj = slot >> 3, f4 = (slot & 7) * 4;
            float4 v = *(const float4*)&src[jj * MLPD + k0 + f4];
            As[jj][f4 + 0] = v.x; As[jj][f4 + 1] = v.y;
            As[jj][f4 + 2] = v.z; As[jj][f4 + 3] = v.w;
        }
#pragma unroll
        for (int it = 0; it < 4; it++) {
            int slot = t + it * 256;
            int kk = slot >> 5, f4 = (slot & 31) * 4;
            float4 v = *(const float4*)&W[(size_t)(k0 + kk) * SDI + c0l + f4];
            *(float4*)&Ws[kk][f4] = v;
        }
        __syncthreads();
#pragma unroll 4
        for (int kx = 0; kx < 32; kx++) {
            float a[4];
#pragma unroll
            for (int jj = 0; jj < 4; jj++) a[jj] = As[j0 + jj][kx];
#pragma unroll
            for (int cf = 0; cf < 4; cf++) {
                float4 wv = *(const float4*)&Ws[kx][tc * 4 + cf * 32];
#pragma unroll
                for (int jj = 0; jj < 4; jj++) {
                    acc[jj][cf * 4 + 0] += a[jj] * wv.x;
                    acc[jj][cf * 4 + 1] += a[jj] * wv.y;
                    acc[jj][cf * 4 + 2] += a[jj] * wv.z;
                    acc[jj][cf * 4 + 3] += a[jj] * wv.w;
                }
            }
        }
    }
#pragma unroll
    for (int jj = 0; jj < 4; jj++)
#pragma unroll
        for (int cf = 0; cf < 4; cf++) {
            float4 v = make_float4(acc[jj][cf * 4 + 0], acc[jj][cf * 4 + 1],
                                   acc[jj][cf * 4 + 2], acc[jj][cf * 4 + 3]);
            *(float4*)&part[(size_t)ks * 655360 + (size_t)(j0 + jj) * 5120 + c0 + tc * 4 + cf * 32] = v;
        }
}

// K4b/K5: widened. grid(128 j, 10), block(512).
// y<5: vals s-chunk reduce -> LDS -> VC; y>=5: pav s-chunk reduce -> global.
__global__ __launch_bounds__(512) void k_post(const float* __restrict__ part,
                                              const float* __restrict__ bv2,
                                              const float* __restrict__ bp2,
                                              const float* __restrict__ Wc,
                                              float* __restrict__ pav,
                                              float* __restrict__ VC) {
    int j = blockIdx.x, y = blockIdx.y, t = threadIdx.x;
    if (y < 5) {
        int s = y;
        __shared__ float vlds[512];
        int e = s * 512 + t;
        float sum = 0.f;
#pragma unroll
        for (int p = 0; p < KSP; p++) sum += part[(size_t)p * 655360 + (size_t)j * 5120 + e];
        vlds[t] = sum + bv2[e];
        __syncthreads();
        int dd = t & 63;
        int hbase = t - dd;
        float acc = 0.f;
#pragma unroll 8
        for (int d2 = 0; d2 < DH_; d2++) acc += vlds[hbase + d2] * Wc[(size_t)(hbase + d2) * DD_ + dd];
        VC[(size_t)(j * SS_ + s) * DI_ + t] = acc;
    } else {
        int s = y - 5;
        int e = 2560 + s * 512 + t;
        float sum = 0.f;
#pragma unroll
        for (int p = 0; p < KSP; p++) sum += part[(size_t)p * 655360 + (size_t)j * 5120 + e];
        pav[(size_t)j * SDI + s * 512 + t] = sum + bp2[s * 512 + t];
    }
}

// K6+K8: fused T-sum + EV + rsd, u-range halved. grid(128 i, 2), block(640).
__global__ __launch_bounds__(640) void k_den(const float* __restrict__ tij,
                                             const float* __restrict__ Wev,
                                             const float* __restrict__ q,
                                             float* __restrict__ rsd) {
    int i = blockIdx.x, half = blockIdx.y, t = threadIdx.x;
    __shared__ float red[10][64];
    __shared__ float Tl[64];
    __shared__ float ql[DI_];
    int c = t & 63, jw = t >> 6;
    float s = 0.f;
    for (int j = jw; j < NN; j += 10) s += tij[(size_t)(i * NN + j) * DD_ + c];
    red[jw][c] = s;
    if (t < DI_) ql[t] = q[i * DI_ + t];
    __syncthreads();
    if (t < 64) {
        float a = 0.f;
#pragma unroll
        for (int r2 = 0; r2 < 10; r2++) a += red[r2][t];
        Tl[t] = a;
    }
    __syncthreads();
#pragma unroll
    for (int kx = 0; kx < 2; kx++) {
        int u = half * 1280 + kx * 640 + t;
        float ev = 0.f;
#pragma unroll 8
        for (int cc = 0; cc < DD_; cc++) ev += Tl[cc] * Wev[(size_t)cc * SDI + u];
        float den = wave_sum64(ev * ql[u & 511]);
        if ((t & 63) == 0) {
            int g = u >> 6;               // = s*8 + h
            int ss = g >> 3, hh = g & 7;
            rsd[i * 40 + hh * SS_ + ss] = 1.0f / den;
        }
    }
}

// K7: sn, head-halved. grid(128, 2), block(512).
__global__ __launch_bounds__(512) void k_simnum(const float* __restrict__ q,
                                                const float* __restrict__ k,
                                                float* __restrict__ sn) {
    int i = blockIdx.x, yh = blockIdx.y, t = threadIdx.x;
    int hh = yh * 4 + (t >> 7), j = t & 127;
    __shared__ float qb[256];
    if (t < 256) qb[t] = q[i * DI_ + yh * 256 + t];
    __syncthreads();
    float a = 0.f;
    const float* kr = &k[(size_t)j * DI_ + hh * DH_];
    const float* qr = &qb[(hh - yh * 4) * DH_];
#pragma unroll 8
    for (int d = 0; d < DH_; d++) a += qr[d] * kr[d];
    sn[i * 1024 + hh * NN + j] = a;
}

// K9: M via MFMA hi/lo bf16 compensation. grid(128,5), block(256)
#define KCM 64
__global__ __launch_bounds__(256) void k_M(const float* __restrict__ pav,
                                           const float* __restrict__ Wev,
                                           const float* __restrict__ Wc,
                                           float* __restrict__ M) {
    int j = blockIdx.x, s = blockIdx.y, t = threadIdx.x;
    int lane = t & 63, w = t >> 6;
    __shared__ float P[DI_];
    __shared__ unsigned short Ahi[64][72], Alo[64][72];
    __shared__ unsigned short Bhi[64][72], Blo[64][72];
    P[t] = pav[j * SDI + s * DI_ + t];
    P[t + 256] = pav[j * SDI + s * DI_ + t + 256];
    f32x4 acc[4];
#pragma unroll
    for (int n = 0; n < 4; n++) acc[n] = (f32x4){0.f, 0.f, 0.f, 0.f};
    __syncthreads();
    for (int u0 = 0; u0 < DI_; u0 += KCM) {
        {
            int c = t >> 2, ug = (t & 3) * 16;
            const float* wevp = &Wev[(size_t)c * SDI + s * DI_ + u0 + ug];
            unsigned short ah[16], al[16];
#pragma unroll
            for (int e = 0; e < 16; e += 4) {
                float4 wv = *(const float4*)(wevp + e);
                float4 pv = *(const float4*)&P[u0 + ug + e];
                float av[4] = {wv.x * pv.x, wv.y * pv.y, wv.z * pv.z, wv.w * pv.w};
#pragma unroll
                for (int z = 0; z < 4; z++) {
                    unsigned short hh2 = f2bf_u(av[z]);
                    ah[e + z] = hh2;
                    al[e + z] = f2bf_u(av[z] - bfu2f(hh2));
                }
            }
            *(uint4*)&Ahi[c][ug] = make_uint4(pk2(ah[0], ah[1]), pk2(ah[2], ah[3]),
                                              pk2(ah[4], ah[5]), pk2(ah[6], ah[7]));
            *(uint4*)&Ahi[c][ug + 8] = make_uint4(pk2(ah[8], ah[9]), pk2(ah[10], ah[11]),
                                                  pk2(ah[12], ah[13]), pk2(ah[14], ah[15]));
            *(uint4*)&Alo[c][ug] = make_uint4(pk2(al[0], al[1]), pk2(al[2], al[3]),
                                              pk2(al[4], al[5]), pk2(al[6], al[7]));
            *(uint4*)&Alo[c][ug + 8] = make_uint4(pk2(al[8], al[9]), pk2(al[10], al[11]),
                                                  pk2(al[12], al[13]), pk2(al[14], al[15]));
        }
        {
            int dd = t & 63, ub = (t >> 6) * 16;
            unsigned short bh[16], bl[16];
#pragma unroll
            for (int e = 0; e < 16; e++) {
                float v = Wc[(size_t)(u0 + ub + e) * DD_ + dd];
                unsigned short hh2 = f2bf_u(v);
                bh[e] = hh2;
                bl[e] = f2bf_u(v - bfu2f(hh2));
            }
            *(uint4*)&Bhi[dd][ub] = make_uint4(pk2(bh[0], bh[1]), pk2(bh[2], bh[3]),
                                               pk2(bh[4], bh[5]), pk2(bh[6], bh[7]));
            *(uint4*)&Bhi[dd][ub + 8] = make_uint4(pk2(bh[8], bh[9]), pk2(bh[10], bh[11]),
                                                   pk2(bh[12], bh[13]), pk2(bh[14], bh[15]));
            *(uint4*)&Blo[dd][ub] = make_uint4(pk2(bl[0], bl[1]), pk2(bl[2], bl[3]),
                                               pk2(bl[4], bl[5]), pk2(bl[6], bl[7]));
            *(uint4*)&Blo[dd][ub + 8] = make_uint4(pk2(bl[8], bl[9]), pk2(bl[10], bl[11]),
                                                   pk2(bl[12], bl[13]), pk2(bl[14], bl[15]));
        }
        __syncthreads();
#pragma unroll
        for (int kk = 0; kk < 2; kk++) {
            int ko = kk * 32 + (lane >> 4) * 8;
            short8 a_h = *(const short8*)&Ahi[w * 16 + (lane & 15)][ko];
            short8 a_l = *(const short8*)&Alo[w * 16 + (lane & 15)][ko];
#pragma unroll
            for (int n = 0; n < 4; n++) {
                short8 b_h = *(const short8*)&Bhi[n * 16 + (lane & 15)][ko];
                short8 b_l = *(const short8*)&Blo[n * 16 + (lane & 15)][ko];
                acc[n] = __builtin_amdgcn_mfma_f32_16x16x32_bf16(a_h, b_h, acc[n], 0, 0, 0);
                acc[n] = __builtin_amdgcn_mfma_f32_16x16x32_bf16(a_h, b_l, acc[n], 0, 0, 0);
                acc[n] = __builtin_amdgcn_mfma_f32_16x16x32_bf16(a_l, b_h, acc[n], 0, 0, 0);
            }
        }
        __syncthreads();
    }
    float* Mp = &M[(size_t)(j * SS_ + s) * 4096];
#pragma unroll
    for (int n = 0; n < 4; n++)
#pragma unroll
        for (int r = 0; r < 4; r++) {
            int c = w * 16 + (lane >> 4) * 4 + r;
            int dd = n * 16 + (lane & 15);
            Mp[c * 64 + dd] = acc[n][r];
        }
}

// K10: out = A + E. grid(128 j, 5 s, 2 ic), block(256). 64 i per block.
__global__ __launch_bounds__(256) void k_out(const float* __restrict__ M, const float* __restrict__ VC,
                      const float* __restrict__ sn, const float* __restrict__ rsd,
                      const float* __restrict__ tij, float* __restrict__ outb) {
    int j = blockIdx.x, s = blockIdx.y, ic = blockIdx.z, t = threadIdx.x;
    int il = t >> 6, dd = t & 63;
    __shared__ float VCl[DI_];
    __shared__ float tl[4][64];
    __shared__ float snl[4][8];
    __shared__ float rl[4][8];
    float Mcol[64];
    const float* Mp = &M[(size_t)(j * SS_ + s) * 4096];
#pragma unroll
    for (int c = 0; c < 64; c++) Mcol[c] = Mp[c * 64 + dd];
    VCl[t] = VC[(j * SS_ + s) * DI_ + t];
    VCl[t + 256] = VC[(j * SS_ + s) * DI_ + t + 256];
    __syncthreads();
    for (int ib = ic * 64; ib < ic * 64 + 64; ib += 4) {
        int i = ib + il;
        tl[il][dd] = tij[(size_t)(i * NN + j) * DD_ + dd];
        if (dd < 8) {
            snl[il][dd] = sn[i * 1024 + dd * NN + j];
            rl[il][dd] = rsd[i * 40 + dd * SS_ + s];
        }
        float A = 0.f;
#pragma unroll
        for (int hh = 0; hh < HH_; hh++) A += snl[il][hh] * rl[il][hh] * VCl[hh * DH_ + dd];
        float E = 0.f;
        const float4* tl4 = (const float4*)&tl[il][0];
#pragma unroll
        for (int c4 = 0; c4 < 16; c4++) {
            float4 tv = tl4[c4];
            E += tv.x * Mcol[4 * c4] + tv.y * Mcol[4 * c4 + 1] +
                 tv.z * Mcol[4 * c4 + 2] + tv.w * Mcol[4 * c4 + 3];
        }
        outb[((size_t)(i * NN + j) * SS_ + s) * 64 + dd] = A + E;
    }
}

// K11a: partial j-reduction. grid(128 i, 16 jc), block(320). 8 j per block.
#define JC 16
#define JPC 8
__global__ void k_red1(const float* __restrict__ outb,
                       const float* __restrict__ r1, const float* __restrict__ r2,
                       const float* __restrict__ x1, const float* __restrict__ x2,
                       float* __restrict__ pr) {
    int i = blockIdx.x, jc = blockIdx.y, t = threadIdx.x;
    int s = t >> 6, dd = t & 63;
    int jbeg = jc * JPC;
    float hacc = 0.f;
    float am[5] = {0.f, 0.f, 0.f, 0.f, 0.f};
    for (int jj = 0; jj < JPC; jj++) {
        int j = jbeg + jj;
        float ov = outb[((size_t)(i * NN + j) * SS_ + s) * 64 + dd];
        if (s == 0) {
            hacc += ov;
        } else if (s == 1) {
#pragma unroll
            for (int m = 0; m < 3; m++) am[m] += r1[(i * NN + j) * 3 + m] * ov;
        } else if (s == 2) {
#pragma unroll
            for (int m = 0; m < 5; m++) am[m] += r2[(i * NN + j) * 5 + m] * ov;
        } else if (s == 3) {
#pragma unroll
            for (int m = 0; m < 3; m++) am[m] += x1[(j * DD_ + dd) * 3 + m] * ov;
        } else {
#pragma unroll
            for (int m = 0; m < 5; m++) am[m] += x2[(j * DD_ + dd) * 5 + m] * ov;
        }
    }
    float* rec = &pr[(size_t)(i * JC + jc) * 1088];
    if (s == 0) {
        rec[dd] = hacc;
    } else if (s == 1) {
#pragma unroll
        for (int m = 0; m < 3; m++) rec[64 + dd * 3 + m] = am[m];
    } else if (s == 2) {
#pragma unroll
        for (int m = 0; m < 5; m++) rec[256 + dd * 5 + m] = am[m];
    } else if (s == 3) {
#pragma unroll
        for (int m = 0; m < 3; m++) rec[576 + dd * 3 + m] = am[m];
    } else {
#pragma unroll
        for (int m = 0; m < 5; m++) rec[768 + dd * 5 + m] = am[m];
    }
}

// K11b: fold 16 partials + combine + store. grid(128), block(320).
__global__ void k_red2(const float* __restrict__ pr, const float* __restrict__ h,
                       float* __restrict__ dst) {
    int i = blockIdx.x, t = threadIdx.x;
    int s = t >> 6, dd = t & 63;
    const float* base = &pr[(size_t)i * JC * 1088];
    if (s == 0) {
        float v = 0.f;
#pragma unroll
        for (int c = 0; c < JC; c++) v += base[c * 1088 + dd];
        dst[i * DD_ + dd] = h[i * DD_ + dd] + v;
    } else if (s == 3) {
        float v[3] = {0.f, 0.f, 0.f};
#pragma unroll
        for (int c = 0; c < JC; c++) {
#pragma unroll
            for (int m = 0; m < 3; m++)
                v[m] += base[c * 1088 + 64 + dd * 3 + m] + base[c * 1088 + 576 + dd * 3 + m];
        }
#pragma unroll
        for (int m = 0; m < 3; m++)
            dst[8192 + (i * DD_ + dd) * 3 + m] = v[m];
    } else if (s == 4) {
        float v[5] = {0.f, 0.f, 0.f, 0.f, 0.f};
#pragma unroll
        for (int c = 0; c < JC; c++) {
#pragma unroll
            for (int m = 0; m < 5; m++)
                v[m] += base[c * 1088 + 256 + dd * 5 + m] + base[c * 1088 + 768 + dd * 5 + m];
        }
#pragma unroll
        for (int m = 0; m < 5; m++)
            dst[8192 + 24576 + (i * DD_ + dd) * 5 + m] = v[m];
    }
}

extern "C" void kernel_launch(void* const* d_in, const int* in_sizes, int n_in,
                              void* d_out, int out_size, void* d_ws, size_t ws_size,
                              hipStream_t stream) {
    const float* h_in = (const float*)d_in[0];
    const float* tij = (const float*)d_in[1];
    const float* r1 = (const float*)d_in[2];
    const float* r2 = (const float*)d_in[3];
    const float* x1 = (const float*)d_in[4];
    const float* x2 = (const float*)d_in[5];
    const float* ghi = (const float*)d_in[6];
    const float* ghj = (const float*)d_in[7];
    const float* Wq = (const float*)d_in[8];
    const float* Wk = (const float*)d_in[9];
    const float* Wv1 = (const float*)d_in[10];
    const float* bv1 = (const float*)d_in[11];
    const float* Wv2 = (const float*)d_in[12];
    const float* bv2 = (const float*)d_in[13];
    const float* Wp1 = (const float*)d_in[14];
    const float* bp1 = (const float*)d_in[15];
    const float* Wp2 = (const float*)d_in[16];
    const float* bp2 = (const float*)d_in[17];
    const float* Wev = (const float*)d_in[18];
    const float* Wc = (const float*)d_in[19];
    float* dst = (float*)d_out;

    float* w = (float*)d_ws;
    size_t off = 16;
    auto alloc = [&](size_t n) { float* p = w + off; off += n; return p; };
    float* q    = alloc(65536);
    float* k    = alloc(65536);
    float* a1   = alloc(131072);
    float* p1   = alloc(131072);
    float* pav  = alloc(327680);
    float* VC   = alloc(327680);
    float* sn   = alloc(131072);
    float* rsd  = alloc(5120);
    float* M    = alloc(2621440);
    float* outb = alloc(5242880);
    float* part = alloc(5242880);   // 8 x 655360 split-K partials
    float* pr   = alloc(2228224);   // 128 x 16 x 1088 j-reduction partials

    k_front<<<dim3(128, 4), dim3(256), 0, stream>>>(h_in, ghi, ghj, Wq, Wk, Wv1, bv1, Wp1, bp1,
                                                    q, k, a1, p1);
    k_mlp2<<<dim3(40, KSP), dim3(256), 0, stream>>>(a1, p1, Wv2, Wp2, part);
    k_post<<<dim3(128, 10), dim3(512), 0, stream>>>(part, bv2, bp2, Wc, pav, VC);
    k_den<<<dim3(128, 2), dim3(640), 0, stream>>>(tij, Wev, q, rsd);
    k_simnum<<<dim3(128, 2), dim3(512), 0, stream>>>(q, k, sn);
    k_M<<<dim3(128, 5), dim3(256), 0, stream>>>(pav, Wev, Wc, M);
    k_out<<<dim3(128, 5, 2), dim3(256), 0, stream>>>(M, VC, sn, rsd, tij, outb);
    k_red1<<<dim3(128, JC), dim3(320), 0, stream>>>(outb, r1, r2, x1, x2, pr);
    k_red2<<<dim3(128), dim3(320), 0, stream>>>(pr, h_in, dst);
}

// Round 8
// 203.872 us; speedup vs baseline: 2.9985x; 1.1988x over previous
//
#include <hip/hip_runtime.h>
#include <hip/hip_bf16.h>

typedef __hip_bfloat16 bf16;
typedef __attribute__((ext_vector_type(8))) short short8;
typedef __attribute__((ext_vector_type(4))) float f32x4;

#define NN 128
#define DD_ 64
#define HH_ 8
#define DH_ 64
#define DI_ 512
#define SS_ 5
#define MLPD 1024
#define SDI 2560

__device__ __forceinline__ float wave_sum64(float v) {
#pragma unroll
    for (int off = 32; off > 0; off >>= 1) v += __shfl_xor(v, off, 64);
    return v;
}

__device__ __forceinline__ unsigned short f2bf_u(float f) {
    unsigned u = __float_as_uint(f);
    u += 0x7FFF + ((u >> 16) & 1);
    return (unsigned short)(u >> 16);
}
__device__ __forceinline__ float bfu2f(unsigned short s) {
    return __uint_as_float(((unsigned)s) << 16);
}
__device__ __forceinline__ unsigned pk2(unsigned short a, unsigned short b) {
    return (unsigned)a | ((unsigned)b << 16);
}

// K1: fused LN + q/k + mlp1, column-chunked. grid(128 i, 4 ch), block(256).
__global__ __launch_bounds__(256) void k_front(
    const float* __restrict__ h, const float* __restrict__ ghi, const float* __restrict__ ghj,
    const float* __restrict__ Wq, const float* __restrict__ Wk,
    const float* __restrict__ Wv1, const float* __restrict__ bv1,
    const float* __restrict__ Wp1, const float* __restrict__ bp1,
    float* __restrict__ q, float* __restrict__ k,
    float* __restrict__ a1, float* __restrict__ p1) {
    int i = blockIdx.x, ch = blockIdx.y, t = threadIdx.x;
    int d = t & 63;
    __shared__ float hib[DD_], hjb[DD_];
    float x = h[i * DD_ + d];
    float s = wave_sum64(x);
    float s2 = wave_sum64(x * x);
    float m = s * (1.0f / DD_);
    float v = s2 * (1.0f / DD_) - m * m;
    float r = rsqrtf(v + 1e-5f);
    float xc = (x - m) * r;
    if (t < 64) { hib[d] = xc * ghi[d]; hjb[d] = xc * ghj[d]; }
    __syncthreads();
    {
        int c = ch * 128 + (t & 127);
        const float* W = (t < 128) ? Wq : Wk;
        const float* hb = (t < 128) ? hib : hjb;
        float a = 0.f;
#pragma unroll 8
        for (int dd = 0; dd < DD_; dd++) a += hb[dd] * W[dd * DI_ + c];
        float* dstqk = (t < 128) ? q : k;
        dstqk[i * DI_ + c] = a;
    }
    {
        int c = ch * 256 + t;
        float av = 0.f, ap = 0.f;
#pragma unroll 4
        for (int dd = 0; dd < DD_; dd++) {
            float hv = hjb[dd];
            av += hv * Wv1[dd * MLPD + c];
            ap += hv * Wp1[dd * MLPD + c];
        }
        float xv = av + bv1[c], xp = ap + bp1[c];
        a1[i * MLPD + c] = xv / (1.0f + expf(-xv));
        p1[i * MLPD + c] = xp / (1.0f + expf(-xp));
    }
}

// K4: split-K MFMA GEMM (hi/lo bf16 compensation): part[ks][j][cc].
// grid(80 ct, 4 ks), block(256). Tile: 128 j x 64 c, K-slice 256 in chunks of 32.
#define KS2 4
__global__ __launch_bounds__(256) void k_mlp2(const float* __restrict__ a1,
                                              const float* __restrict__ p1,
                                              const float* __restrict__ Wv2,
                                              const float* __restrict__ Wp2,
                                              float* __restrict__ part) {
    int ct = blockIdx.x, ks = blockIdx.y, t = threadIdx.x;
    int c0 = ct * 64;
    bool isp = c0 >= 2560;
    int c0l = c0 - (isp ? 2560 : 0);
    const float* __restrict__ src = isp ? p1 : a1;
    const float* __restrict__ W = isp ? Wp2 : Wv2;
    int kbase = ks * 256;
    __shared__ unsigned short Ahi[128][40], Alo[128][40];
    __shared__ unsigned short Bhi[64][40], Blo[64][40];
    int lane = t & 63, wv = t >> 6;
    int l15 = lane & 15, quad = lane >> 4;
    f32x4 acc[2][4];
#pragma unroll
    for (int mt = 0; mt < 2; mt++)
#pragma unroll
        for (int nt = 0; nt < 4; nt++) acc[mt][nt] = (f32x4){0.f, 0.f, 0.f, 0.f};
    int aj = t >> 1, ak = (t & 1) * 16;
    int bc = t & 63, bk = (t >> 6) * 8;
    for (int kc = 0; kc < 8; kc++) {
        int k0 = kbase + kc * 32;
        __syncthreads();
        // stage A (128 j x 32 k) hi/lo
        {
            unsigned short h16[16], l16[16];
            const float* ap = &src[(size_t)aj * MLPD + k0 + ak];
#pragma unroll
            for (int e = 0; e < 16; e += 4) {
                float4 v = *(const float4*)(ap + e);
                float vv[4] = {v.x, v.y, v.z, v.w};
#pragma unroll
                for (int z = 0; z < 4; z++) {
                    unsigned short hb = f2bf_u(vv[z]);
                    h16[e + z] = hb;
                    l16[e + z] = f2bf_u(vv[z] - bfu2f(hb));
                }
            }
            *(uint4*)&Ahi[aj][ak] = make_uint4(pk2(h16[0], h16[1]), pk2(h16[2], h16[3]),
                                               pk2(h16[4], h16[5]), pk2(h16[6], h16[7]));
            *(uint4*)&Ahi[aj][ak + 8] = make_uint4(pk2(h16[8], h16[9]), pk2(h16[10], h16[11]),
                                                   pk2(h16[12], h16[13]), pk2(h16[14], h16[15]));
            *(uint4*)&Alo[aj][ak] = make_uint4(pk2(l16[0], l16[1]), pk2(l16[2], l16[3]),
                                               pk2(l16[4], l16[5]), pk2(l16[6], l16[7]));
            *(uint4*)&Alo[aj][ak + 8] = make_uint4(pk2(l16[8], l16[9]), pk2(l16[10], l16[11]),
                                                   pk2(l16[12], l16[13]), pk2(l16[14], l16[15]));
        }
        // stage B (32 k x 64 c) -> transposed hi/lo via register pack
        {
            unsigned short h8[8], l8[8];
#pragma unroll
            for (int e = 0; e < 8; e++) {
                float v = W[(size_t)(k0 + bk + e) * SDI + c0l + bc];
                unsigned short hb = f2bf_u(v);
                h8[e] = hb;
                l8[e] = f2bf_u(v - bfu2f(hb));
            }
            *(uint4*)&Bhi[bc][bk] = make_uint4(pk2(h8[0], h8[1]), pk2(h8[2], h8[3]),
                                               pk2(h8[4], h8[5]), pk2(h8[6], h8[7]));
            *(uint4*)&Blo[bc][bk] = make_uint4(pk2(l8[0], l8[1]), pk2(l8[2], l8[3]),
                                               pk2(l8[4], l8[5]), pk2(l8[6], l8[7]));
        }
        __syncthreads();
        int ko = quad * 8;
        short8 a_h0 = *(const short8*)&Ahi[(wv * 2 + 0) * 16 + l15][ko];
        short8 a_l0 = *(const short8*)&Alo[(wv * 2 + 0) * 16 + l15][ko];
        short8 a_h1 = *(const short8*)&Ahi[(wv * 2 + 1) * 16 + l15][ko];
        short8 a_l1 = *(const short8*)&Alo[(wv * 2 + 1) * 16 + l15][ko];
#pragma unroll
        for (int nt = 0; nt < 4; nt++) {
            short8 b_h = *(const short8*)&Bhi[nt * 16 + l15][ko];
            short8 b_l = *(const short8*)&Blo[nt * 16 + l15][ko];
            acc[0][nt] = __builtin_amdgcn_mfma_f32_16x16x32_bf16(a_h0, b_h, acc[0][nt], 0, 0, 0);
            acc[0][nt] = __builtin_amdgcn_mfma_f32_16x16x32_bf16(a_h0, b_l, acc[0][nt], 0, 0, 0);
            acc[0][nt] = __builtin_amdgcn_mfma_f32_16x16x32_bf16(a_l0, b_h, acc[0][nt], 0, 0, 0);
            acc[1][nt] = __builtin_amdgcn_mfma_f32_16x16x32_bf16(a_h1, b_h, acc[1][nt], 0, 0, 0);
            acc[1][nt] = __builtin_amdgcn_mfma_f32_16x16x32_bf16(a_h1, b_l, acc[1][nt], 0, 0, 0);
            acc[1][nt] = __builtin_amdgcn_mfma_f32_16x16x32_bf16(a_l1, b_h, acc[1][nt], 0, 0, 0);
        }
    }
#pragma unroll
    for (int mt = 0; mt < 2; mt++)
#pragma unroll
        for (int nt = 0; nt < 4; nt++)
#pragma unroll
            for (int r = 0; r < 4; r++) {
                int j = (wv * 2 + mt) * 16 + quad * 4 + r;
                int cc = c0 + nt * 16 + l15;
                part[(size_t)ks * 655360 + (size_t)j * 5120 + cc] = acc[mt][nt][r];
            }
}

// K4b/K5: reduce partials + bias -> VC / pav. grid(128 j, 10), block(512).
__global__ __launch_bounds__(512) void k_post(const float* __restrict__ part,
                                              const float* __restrict__ bv2,
                                              const float* __restrict__ bp2,
                                              const float* __restrict__ Wc,
                                              float* __restrict__ pav,
                                              float* __restrict__ VC) {
    int j = blockIdx.x, y = blockIdx.y, t = threadIdx.x;
    if (y < 5) {
        int s = y;
        __shared__ float vlds[512];
        int e = s * 512 + t;
        float sum = 0.f;
#pragma unroll
        for (int p = 0; p < KS2; p++) sum += part[(size_t)p * 655360 + (size_t)j * 5120 + e];
        vlds[t] = sum + bv2[e];
        __syncthreads();
        int dd = t & 63;
        int hbase = t - dd;
        float acc = 0.f;
#pragma unroll 8
        for (int d2 = 0; d2 < DH_; d2++) acc += vlds[hbase + d2] * Wc[(size_t)(hbase + d2) * DD_ + dd];
        VC[(size_t)(j * SS_ + s) * DI_ + t] = acc;
    } else {
        int s = y - 5;
        int e = 2560 + s * 512 + t;
        float sum = 0.f;
#pragma unroll
        for (int p = 0; p < KS2; p++) sum += part[(size_t)p * 655360 + (size_t)j * 5120 + e];
        pav[(size_t)j * SDI + s * 512 + t] = sum + bp2[s * 512 + t];
    }
}

// K6+K8: fused T-sum + EV + rsd. grid(128 i, 2), block(640).
__global__ __launch_bounds__(640) void k_den(const float* __restrict__ tij,
                                             const float* __restrict__ Wev,
                                             const float* __restrict__ q,
                                             float* __restrict__ rsd) {
    int i = blockIdx.x, half = blockIdx.y, t = threadIdx.x;
    __shared__ float red[10][64];
    __shared__ float Tl[64];
    __shared__ float ql[DI_];
    int c = t & 63, jw = t >> 6;
    float s = 0.f;
    for (int j = jw; j < NN; j += 10) s += tij[(size_t)(i * NN + j) * DD_ + c];
    red[jw][c] = s;
    if (t < DI_) ql[t] = q[i * DI_ + t];
    __syncthreads();
    if (t < 64) {
        float a = 0.f;
#pragma unroll
        for (int r2 = 0; r2 < 10; r2++) a += red[r2][t];
        Tl[t] = a;
    }
    __syncthreads();
#pragma unroll
    for (int kx = 0; kx < 2; kx++) {
        int u = half * 1280 + kx * 640 + t;
        float ev = 0.f;
#pragma unroll 8
        for (int cc = 0; cc < DD_; cc++) ev += Tl[cc] * Wev[(size_t)cc * SDI + u];
        float den = wave_sum64(ev * ql[u & 511]);
        if ((t & 63) == 0) {
            int g = u >> 6;
            int ss = g >> 3, hh = g & 7;
            rsd[i * 40 + hh * SS_ + ss] = 1.0f / den;
        }
    }
}

// K7: sn. grid(128, 2), block(512).
__global__ __launch_bounds__(512) void k_simnum(const float* __restrict__ q,
                                                const float* __restrict__ k,
                                                float* __restrict__ sn) {
    int i = blockIdx.x, yh = blockIdx.y, t = threadIdx.x;
    int hh = yh * 4 + (t >> 7), j = t & 127;
    __shared__ float qb[256];
    if (t < 256) qb[t] = q[i * DI_ + yh * 256 + t];
    __syncthreads();
    float a = 0.f;
    const float* kr = &k[(size_t)j * DI_ + hh * DH_];
    const float* qr = &qb[(hh - yh * 4) * DH_];
#pragma unroll 8
    for (int d = 0; d < DH_; d++) a += qr[d] * kr[d];
    sn[i * 1024 + hh * NN + j] = a;
}

// K9: M via MFMA hi/lo bf16 compensation. grid(128,5), block(256)
#define KCM 64
__global__ __launch_bounds__(256) void k_M(const float* __restrict__ pav,
                                           const float* __restrict__ Wev,
                                           const float* __restrict__ Wc,
                                           float* __restrict__ M) {
    int j = blockIdx.x, s = blockIdx.y, t = threadIdx.x;
    int lane = t & 63, w = t >> 6;
    __shared__ float P[DI_];
    __shared__ unsigned short Ahi[64][72], Alo[64][72];
    __shared__ unsigned short Bhi[64][72], Blo[64][72];
    P[t] = pav[j * SDI + s * DI_ + t];
    P[t + 256] = pav[j * SDI + s * DI_ + t + 256];
    f32x4 acc[4];
#pragma unroll
    for (int n = 0; n < 4; n++) acc[n] = (f32x4){0.f, 0.f, 0.f, 0.f};
    __syncthreads();
    for (int u0 = 0; u0 < DI_; u0 += KCM) {
        {
            int c = t >> 2, ug = (t & 3) * 16;
            const float* wevp = &Wev[(size_t)c * SDI + s * DI_ + u0 + ug];
            unsigned short ah[16], al[16];
#pragma unroll
            for (int e = 0; e < 16; e += 4) {
                float4 wv = *(const float4*)(wevp + e);
                float4 pv = *(const float4*)&P[u0 + ug + e];
                float av[4] = {wv.x * pv.x, wv.y * pv.y, wv.z * pv.z, wv.w * pv.w};
#pragma unroll
                for (int z = 0; z < 4; z++) {
                    unsigned short hh2 = f2bf_u(av[z]);
                    ah[e + z] = hh2;
                    al[e + z] = f2bf_u(av[z] - bfu2f(hh2));
                }
            }
            *(uint4*)&Ahi[c][ug] = make_uint4(pk2(ah[0], ah[1]), pk2(ah[2], ah[3]),
                                              pk2(ah[4], ah[5]), pk2(ah[6], ah[7]));
            *(uint4*)&Ahi[c][ug + 8] = make_uint4(pk2(ah[8], ah[9]), pk2(ah[10], ah[11]),
                                                  pk2(ah[12], ah[13]), pk2(ah[14], ah[15]));
            *(uint4*)&Alo[c][ug] = make_uint4(pk2(al[0], al[1]), pk2(al[2], al[3]),
                                              pk2(al[4], al[5]), pk2(al[6], al[7]));
            *(uint4*)&Alo[c][ug + 8] = make_uint4(pk2(al[8], al[9]), pk2(al[10], al[11]),
                                                  pk2(al[12], al[13]), pk2(al[14], al[15]));
        }
        {
            int dd = t & 63, ub = (t >> 6) * 16;
            unsigned short bh[16], bl[16];
#pragma unroll
            for (int e = 0; e < 16; e++) {
                float v = Wc[(size_t)(u0 + ub + e) * DD_ + dd];
                unsigned short hh2 = f2bf_u(v);
                bh[e] = hh2;
                bl[e] = f2bf_u(v - bfu2f(hh2));
            }
            *(uint4*)&Bhi[dd][ub] = make_uint4(pk2(bh[0], bh[1]), pk2(bh[2], bh[3]),
                                               pk2(bh[4], bh[5]), pk2(bh[6], bh[7]));
            *(uint4*)&Bhi[dd][ub + 8] = make_uint4(pk2(bh[8], bh[9]), pk2(bh[10], bh[11]),
                                                   pk2(bh[12], bh[13]), pk2(bh[14], bh[15]));
            *(uint4*)&Blo[dd][ub] = make_uint4(pk2(bl[0], bl[1]), pk2(bl[2], bl[3]),
                                               pk2(bl[4], bl[5]), pk2(bl[6], bl[7]));
            *(uint4*)&Blo[dd][ub + 8] = make_uint4(pk2(bl[8], bl[9]), pk2(bl[10], bl[11]),
                                                   pk2(bl[12], bl[13]), pk2(bl[14], bl[15]));
        }
        __syncthreads();
#pragma unroll
        for (int kk = 0; kk < 2; kk++) {
            int ko = kk * 32 + (lane >> 4) * 8;
            short8 a_h = *(const short8*)&Ahi[w * 16 + (lane & 15)][ko];
            short8 a_l = *(const short8*)&Alo[w * 16 + (lane & 15)][ko];
#pragma unroll
            for (int n = 0; n < 4; n++) {
                short8 b_h = *(const short8*)&Bhi[n * 16 + (lane & 15)][ko];
                short8 b_l = *(const short8*)&Blo[n * 16 + (lane & 15)][ko];
                acc[n] = __builtin_amdgcn_mfma_f32_16x16x32_bf16(a_h, b_h, acc[n], 0, 0, 0);
                acc[n] = __builtin_amdgcn_mfma_f32_16x16x32_bf16(a_h, b_l, acc[n], 0, 0, 0);
                acc[n] = __builtin_amdgcn_mfma_f32_16x16x32_bf16(a_l, b_h, acc[n], 0, 0, 0);
            }
        }
        __syncthreads();
    }
    float* Mp = &M[(size_t)(j * SS_ + s) * 4096];
#pragma unroll
    for (int n = 0; n < 4; n++)
#pragma unroll
        for (int r = 0; r < 4; r++) {
            int c = w * 16 + (lane >> 4) * 4 + r;
            int dd = n * 16 + (lane & 15);
            Mp[c * 64 + dd] = acc[n][r];
        }
}

// K10: out = (t_ij @ M) + (snr @ VC) via MFMA (hi/lo comp). grid(128 j, 5 s), block(256).
// K layout: chunk -1 = snr/VC (8 real k + 24 zero), chunks 0,1 = t/M (c 0..31, 32..63).
__global__ __launch_bounds__(256) void k_out(const float* __restrict__ M, const float* __restrict__ VC,
                                             const float* __restrict__ sn, const float* __restrict__ rsd,
                                             const float* __restrict__ tij, float* __restrict__ outb) {
    int j = blockIdx.x, s = blockIdx.y, t = threadIdx.x;
    int lane = t & 63, wv = t >> 6, l15 = lane & 15, quad = lane >> 4;
    __shared__ unsigned short Ahi[128][40], Alo[128][40];
    __shared__ unsigned short Bhi[64][40], Blo[64][40];
    f32x4 acc[2][4];
#pragma unroll
    for (int mt = 0; mt < 2; mt++)
#pragma unroll
        for (int nt = 0; nt < 4; nt++) acc[mt][nt] = (f32x4){0.f, 0.f, 0.f, 0.f};
    // ---- phase 0: snr (A) / VC (B), k 0..7 data, 8..31 zero
    {
        int i = t >> 1, hg = (t & 1) * 4;
        unsigned short h4[4], l4[4];
#pragma unroll
        for (int e = 0; e < 4; e++) {
            int hh_ = hg + e;
            float v = sn[i * 1024 + hh_ * NN + j] * rsd[i * 40 + hh_ * SS_ + s];
            unsigned short hb = f2bf_u(v);
            h4[e] = hb;
            l4[e] = f2bf_u(v - bfu2f(hb));
        }
        *(uint2*)&Ahi[i][hg] = make_uint2(pk2(h4[0], h4[1]), pk2(h4[2], h4[3]));
        *(uint2*)&Alo[i][hg] = make_uint2(pk2(l4[0], l4[1]), pk2(l4[2], l4[3]));
#pragma unroll
        for (int r = 0; r < 2; r++) {
            int idx = t + r * 256;
            if (idx < 384) {
                int ii = idx / 3, g = idx % 3;
                *(uint4*)&Ahi[ii][8 + g * 8] = make_uint4(0, 0, 0, 0);
                *(uint4*)&Alo[ii][8 + g * 8] = make_uint4(0, 0, 0, 0);
            }
        }
        if (t < 64) {
            unsigned short h8[8], l8[8];
#pragma unroll
            for (int e = 0; e < 8; e++) {
                float v = VC[(size_t)(j * SS_ + s) * DI_ + e * 64 + t];
                unsigned short hb = f2bf_u(v);
                h8[e] = hb;
                l8[e] = f2bf_u(v - bfu2f(hb));
            }
            *(uint4*)&Bhi[t][0] = make_uint4(pk2(h8[0], h8[1]), pk2(h8[2], h8[3]),
                                             pk2(h8[4], h8[5]), pk2(h8[6], h8[7]));
            *(uint4*)&Blo[t][0] = make_uint4(pk2(l8[0], l8[1]), pk2(l8[2], l8[3]),
                                             pk2(l8[4], l8[5]), pk2(l8[6], l8[7]));
        } else {
            int idx = t - 64;  // 192 threads cover 64 rows x 3 groups
            int dd2 = idx / 3, g = idx % 3;
            *(uint4*)&Bhi[dd2][8 + g * 8] = make_uint4(0, 0, 0, 0);
            *(uint4*)&Blo[dd2][8 + g * 8] = make_uint4(0, 0, 0, 0);
        }
    }
    __syncthreads();
    {
        int ko = quad * 8;
        short8 a_h0 = *(const short8*)&Ahi[(wv * 2 + 0) * 16 + l15][ko];
        short8 a_l0 = *(const short8*)&Alo[(wv * 2 + 0) * 16 + l15][ko];
        short8 a_h1 = *(const short8*)&Ahi[(wv * 2 + 1) * 16 + l15][ko];
        short8 a_l1 = *(const short8*)&Alo[(wv * 2 + 1) * 16 + l15][ko];
#pragma unroll
        for (int nt = 0; nt < 4; nt++) {
            short8 b_h = *(const short8*)&Bhi[nt * 16 + l15][ko];
            short8 b_l = *(const short8*)&Blo[nt * 16 + l15][ko];
            acc[0][nt] = __builtin_amdgcn_mfma_f32_16x16x32_bf16(a_h0, b_h, acc[0][nt], 0, 0, 0);
            acc[0][nt] = __builtin_amdgcn_mfma_f32_16x16x32_bf16(a_h0, b_l, acc[0][nt], 0, 0, 0);
            acc[0][nt] = __builtin_amdgcn_mfma_f32_16x16x32_bf16(a_l0, b_h, acc[0][nt], 0, 0, 0);
            acc[1][nt] = __builtin_amdgcn_mfma_f32_16x16x32_bf16(a_h1, b_h, acc[1][nt], 0, 0, 0);
            acc[1][nt] = __builtin_amdgcn_mfma_f32_16x16x32_bf16(a_h1, b_l, acc[1][nt], 0, 0, 0);
            acc[1][nt] = __builtin_amdgcn_mfma_f32_16x16x32_bf16(a_l1, b_h, acc[1][nt], 0, 0, 0);
        }
    }
    // ---- chunks 0,1: A = t_ij rows (c-halves), B = M^T
    for (int kc = 0; kc < 2; kc++) {
        __syncthreads();
        {
            int i = t >> 1, chalf = (t & 1) * 16;
            unsigned short h16[16], l16[16];
            const float* tp = &tij[(size_t)(i * NN + j) * DD_ + kc * 32 + chalf];
#pragma unroll
            for (int e = 0; e < 16; e += 4) {
                float4 v = *(const float4*)(tp + e);
                float vv[4] = {v.x, v.y, v.z, v.w};
#pragma unroll
                for (int z = 0; z < 4; z++) {
                    unsigned short hb = f2bf_u(vv[z]);
                    h16[e + z] = hb;
                    l16[e + z] = f2bf_u(vv[z] - bfu2f(hb));
                }
            }
            *(uint4*)&Ahi[i][chalf] = make_uint4(pk2(h16[0], h16[1]), pk2(h16[2], h16[3]),
                                                 pk2(h16[4], h16[5]), pk2(h16[6], h16[7]));
            *(uint4*)&Ahi[i][chalf + 8] = make_uint4(pk2(h16[8], h16[9]), pk2(h16[10], h16[11]),
                                                     pk2(h16[12], h16[13]), pk2(h16[14], h16[15]));
            *(uint4*)&Alo[i][chalf] = make_uint4(pk2(l16[0], l16[1]), pk2(l16[2], l16[3]),
                                                 pk2(l16[4], l16[5]), pk2(l16[6], l16[7]));
            *(uint4*)&Alo[i][chalf + 8] = make_uint4(pk2(l16[8], l16[9]), pk2(l16[10], l16[11]),
                                                     pk2(l16[12], l16[13]), pk2(l16[14], l16[15]));
        }
        {
            int dd2 = t & 63, cg = (t >> 6) * 8;
            unsigned short h8[8], l8[8];
#pragma unroll
            for (int e = 0; e < 8; e++) {
                float v = M[(size_t)(j * SS_ + s) * 4096 + (size_t)(kc * 32 + cg + e) * 64 + dd2];
                unsigned short hb = f2bf_u(v);
                h8[e] = hb;
                l8[e] = f2bf_u(v - bfu2f(hb));
            }
            *(uint4*)&Bhi[dd2][cg] = make_uint4(pk2(h8[0], h8[1]), pk2(h8[2], h8[3]),
                                                pk2(h8[4], h8[5]), pk2(h8[6], h8[7]));
            *(uint4*)&Blo[dd2][cg] = make_uint4(pk2(l8[0], l8[1]), pk2(l8[2], l8[3]),
                                                pk2(l8[4], l8[5]), pk2(l8[6], l8[7]));
        }
        __syncthreads();
        int ko = quad * 8;
        short8 a_h0 = *(const short8*)&Ahi[(wv * 2 + 0) * 16 + l15][ko];
        short8 a_l0 = *(const short8*)&Alo[(wv * 2 + 0) * 16 + l15][ko];
        short8 a_h1 = *(const short8*)&Ahi[(wv * 2 + 1) * 16 + l15][ko];
        short8 a_l1 = *(const short8*)&Alo[(wv * 2 + 1) * 16 + l15][ko];
#pragma unroll
        for (int nt = 0; nt < 4; nt++) {
            short8 b_h = *(const short8*)&Bhi[nt * 16 + l15][ko];
            short8 b_l = *(const short8*)&Blo[nt * 16 + l15][ko];
            acc[0][nt] = __builtin_amdgcn_mfma_f32_16x16x32_bf16(a_h0, b_h, acc[0][nt], 0, 0, 0);
            acc[0][nt] = __builtin_amdgcn_mfma_f32_16x16x32_bf16(a_h0, b_l, acc[0][nt], 0, 0, 0);
            acc[0][nt] = __builtin_amdgcn_mfma_f32_16x16x32_bf16(a_l0, b_h, acc[0][nt], 0, 0, 0);
            acc[1][nt] = __builtin_amdgcn_mfma_f32_16x16x32_bf16(a_h1, b_h, acc[1][nt], 0, 0, 0);
            acc[1][nt] = __builtin_amdgcn_mfma_f32_16x16x32_bf16(a_h1, b_l, acc[1][nt], 0, 0, 0);
            acc[1][nt] = __builtin_amdgcn_mfma_f32_16x16x32_bf16(a_l1, b_h, acc[1][nt], 0, 0, 0);
        }
    }
#pragma unroll
    for (int mt = 0; mt < 2; mt++)
#pragma unroll
        for (int nt = 0; nt < 4; nt++)
#pragma unroll
            for (int r = 0; r < 4; r++) {
                int i = (wv * 2 + mt) * 16 + quad * 4 + r;
                int dd = nt * 16 + l15;
                outb[((size_t)(i * NN + j) * SS_ + s) * 64 + dd] = acc[mt][nt][r];
            }
}

// K11a: partial j-reduction. grid(128 i, 16 jc), block(320). 8 j per block.
#define JC 16
#define JPC 8
__global__ void k_red1(const float* __restrict__ outb,
                       const float* __restrict__ r1, const float* __restrict__ r2,
                       const float* __restrict__ x1, const float* __restrict__ x2,
                       float* __restrict__ pr) {
    int i = blockIdx.x, jc = blockIdx.y, t = threadIdx.x;
    int s = t >> 6, dd = t & 63;
    int jbeg = jc * JPC;
    float hacc = 0.f;
    float am[5] = {0.f, 0.f, 0.f, 0.f, 0.f};
    for (int jj = 0; jj < JPC; jj++) {
        int j = jbeg + jj;
        float ov = outb[((size_t)(i * NN + j) * SS_ + s) * 64 + dd];
        if (s == 0) {
            hacc += ov;
        } else if (s == 1) {
#pragma unroll
            for (int m = 0; m < 3; m++) am[m] += r1[(i * NN + j) * 3 + m] * ov;
        } else if (s == 2) {
#pragma unroll
            for (int m = 0; m < 5; m++) am[m] += r2[(i * NN + j) * 5 + m] * ov;
        } else if (s == 3) {
#pragma unroll
            for (int m = 0; m < 3; m++) am[m] += x1[(j * DD_ + dd) * 3 + m] * ov;
        } else {
#pragma unroll
            for (int m = 0; m < 5; m++) am[m] += x2[(j * DD_ + dd) * 5 + m] * ov;
        }
    }
    float* rec = &pr[(size_t)(i * JC + jc) * 1088];
    if (s == 0) {
        rec[dd] = hacc;
    } else if (s == 1) {
#pragma unroll
        for (int m = 0; m < 3; m++) rec[64 + dd * 3 + m] = am[m];
    } else if (s == 2) {
#pragma unroll
        for (int m = 0; m < 5; m++) rec[256 + dd * 5 + m] = am[m];
    } else if (s == 3) {
#pragma unroll
        for (int m = 0; m < 3; m++) rec[576 + dd * 3 + m] = am[m];
    } else {
#pragma unroll
        for (int m = 0; m < 5; m++) rec[768 + dd * 5 + m] = am[m];
    }
}

// K11b: fold 16 partials + combine + store. grid(128), block(320).
__global__ void k_red2(const float* __restrict__ pr, const float* __restrict__ h,
                       float* __restrict__ dst) {
    int i = blockIdx.x, t = threadIdx.x;
    int s = t >> 6, dd = t & 63;
    const float* base = &pr[(size_t)i * JC * 1088];
    if (s == 0) {
        float v = 0.f;
#pragma unroll
        for (int c = 0; c < JC; c++) v += base[c * 1088 + dd];
        dst[i * DD_ + dd] = h[i * DD_ + dd] + v;
    } else if (s == 3) {
        float v[3] = {0.f, 0.f, 0.f};
#pragma unroll
        for (int c = 0; c < JC; c++) {
#pragma unroll
            for (int m = 0; m < 3; m++)
                v[m] += base[c * 1088 + 64 + dd * 3 + m] + base[c * 1088 + 576 + dd * 3 + m];
        }
#pragma unroll
        for (int m = 0; m < 3; m++)
            dst[8192 + (i * DD_ + dd) * 3 + m] = v[m];
    } else if (s == 4) {
        float v[5] = {0.f, 0.f, 0.f, 0.f, 0.f};
#pragma unroll
        for (int c = 0; c < JC; c++) {
#pragma unroll
            for (int m = 0; m < 5; m++)
                v[m] += base[c * 1088 + 256 + dd * 5 + m] + base[c * 1088 + 768 + dd * 5 + m];
        }
#pragma unroll
        for (int m = 0; m < 5; m++)
            dst[8192 + 24576 + (i * DD_ + dd) * 5 + m] = v[m];
    }
}

extern "C" void kernel_launch(void* const* d_in, const int* in_sizes, int n_in,
                              void* d_out, int out_size, void* d_ws, size_t ws_size,
                              hipStream_t stream) {
    const float* h_in = (const float*)d_in[0];
    const float* tij = (const float*)d_in[1];
    const float* r1 = (const float*)d_in[2];
    const float* r2 = (const float*)d_in[3];
    const float* x1 = (const float*)d_in[4];
    const float* x2 = (const float*)d_in[5];
    const float* ghi = (const float*)d_in[6];
    const float* ghj = (const float*)d_in[7];
    const float* Wq = (const float*)d_in[8];
    const float* Wk = (const float*)d_in[9];
    const float* Wv1 = (const float*)d_in[10];
    const float* bv1 = (const float*)d_in[11];
    const float* Wv2 = (const float*)d_in[12];
    const float* bv2 = (const float*)d_in[13];
    const float* Wp1 = (const float*)d_in[14];
    const float* bp1 = (const float*)d_in[15];
    const float* Wp2 = (const float*)d_in[16];
    const float* bp2 = (const float*)d_in[17];
    const float* Wev = (const float*)d_in[18];
    const float* Wc = (const float*)d_in[19];
    float* dst = (float*)d_out;

    float* w = (float*)d_ws;
    size_t off = 16;
    auto alloc = [&](size_t n) { float* p = w + off; off += n; return p; };
    float* q    = alloc(65536);
    float* k    = alloc(65536);
    float* a1   = alloc(131072);
    float* p1   = alloc(131072);
    float* pav  = alloc(327680);
    float* VC   = alloc(327680);
    float* sn   = alloc(131072);
    float* rsd  = alloc(5120);
    float* M    = alloc(2621440);
    float* outb = alloc(5242880);
    float* part = alloc(2621440);   // 4 x 655360 split-K partials
    float* pr   = alloc(2228224);   // 128 x 16 x 1088 j-reduction partials

    k_front<<<dim3(128, 4), dim3(256), 0, stream>>>(h_in, ghi, ghj, Wq, Wk, Wv1, bv1, Wp1, bp1,
                                                    q, k, a1, p1);
    k_mlp2<<<dim3(80, KS2), dim3(256), 0, stream>>>(a1, p1, Wv2, Wp2, part);
    k_post<<<dim3(128, 10), dim3(512), 0, stream>>>(part, bv2, bp2, Wc, pav, VC);
    k_den<<<dim3(128, 2), dim3(640), 0, stream>>>(tij, Wev, q, rsd);
    k_simnum<<<dim3(128, 2), dim3(512), 0, stream>>>(q, k, sn);
    k_M<<<dim3(128, 5), dim3(256), 0, stream>>>(pav, Wev, Wc, M);
    k_out<<<dim3(128, 5), dim3(256), 0, stream>>>(M, VC, sn, rsd, tij, outb);
    k_red1<<<dim3(128, JC), dim3(320), 0, stream>>>(outb, r1, r2, x1, x2, pr);
    k_red2<<<dim3(128), dim3(320), 0, stream>>>(pr, h_in, dst);
}